// Round 1
// baseline (383.413 us; speedup 1.0000x reference)
//
#include <hip/hip_runtime.h>

typedef unsigned short u16;
typedef unsigned int u32;
typedef __attribute__((ext_vector_type(8))) short bf16x8;
typedef __attribute__((ext_vector_type(4))) float f32x4;

__device__ __forceinline__ u16 f2bf(float f) {
  union { float f; unsigned int u; } x;
  x.f = f;
  unsigned int r = x.u + 0x7fffu + ((x.u >> 16) & 1u);
  return (u16)(r >> 16);
}

__device__ __forceinline__ float bf2f(u16 v) {
  union { unsigned int u; float f; } x;
  x.u = ((unsigned int)v) << 16;
  return x.f;
}

__device__ __forceinline__ u32 fbits(float f) {
  union { float f; u32 u; } x; x.f = f; return x.u;
}

__device__ __forceinline__ void async16(const u16* g, u16* l) {
  __builtin_amdgcn_global_load_lds((const __attribute__((address_space(1))) void*)g,
                                   (__attribute__((address_space(3))) void*)l, 16, 0, 0);
}

// Stage 128 rows x 64 cols bf16 tile (256 threads). LDS slot s: row=s>>3, stored chunk (s&7)
// holds global 16B chunk c = (s&7) ^ (row&7)  (XOR swizzle -> conflict-free b128 reads).
__device__ __forceinline__ void stage128x64(const u16* __restrict__ src, long row0, int k0,
                                            int ld, u16* lds, int wave, int lane) {
#pragma unroll
  for (int r = 0; r < 4; ++r) {
    int s = r * 256 + wave * 64 + lane;
    int row = s >> 3;
    int c = (s & 7) ^ (row & 7);
    async16(src + (row0 + row) * (long)ld + k0 + c * 8, lds + (r * 256 + wave * 64) * 8);
  }
}

// Same 128x64 half-tile staging, but for a 512-thread block (2 issues/thread).
__device__ __forceinline__ void stage_half512(const u16* __restrict__ src, long row0, int k0,
                                              int ld, u16* lbase, int wave, int lane) {
#pragma unroll
  for (int r = 0; r < 2; ++r) {
    int s = r * 512 + wave * 64 + lane;
    int row = s >> 3;
    int c = (s & 7) ^ (row & 7);
    async16(src + (row0 + row) * (long)ld + k0 + c * 8, lbase + (r * 512 + wave * 64) * 8);
  }
}

// Stage 64 rows x 128 cols (V^T tile): 16 chunks/row, swizzle c = (s&15)^(row&15).
__device__ __forceinline__ void stage64x128(const u16* __restrict__ src, int col0, int ld,
                                            u16* lds, int wave, int lane) {
#pragma unroll
  for (int r = 0; r < 4; ++r) {
    int s = r * 256 + wave * 64 + lane;
    int row = s >> 4;
    int c = (s & 15) ^ (row & 15);
    async16(src + (long)row * ld + col0 + c * 8, lds + (r * 256 + wave * 64) * 8);
  }
}

// ---------------- LayerNorm core (torch-style: unbiased std, /(std+eps)) ----------------
__device__ __forceinline__ void ln_core(float4 v, const float* g, const float* b, int t,
                                        u16* outrow) {
  float s = v.x + v.y + v.z + v.w;
  float ss = v.x * v.x + v.y * v.y + v.z * v.z + v.w * v.w;
#pragma unroll
  for (int off = 32; off; off >>= 1) {
    s += __shfl_xor(s, off);
    ss += __shfl_xor(ss, off);
  }
  __shared__ float red[8];
  int wave = t >> 6, lane = t & 63;
  if (lane == 0) { red[wave] = s; red[wave + 4] = ss; }
  __syncthreads();
  float tot = red[0] + red[1] + red[2] + red[3];
  float tots = red[4] + red[5] + red[6] + red[7];
  float mean = tot * (1.0f / 1024.0f);
  float var = (tots - 1024.0f * mean * mean) * (1.0f / 1023.0f);
  var = fmaxf(var, 0.0f);
  float inv = 1.0f / (sqrtf(var) + 1e-6f);
  float4 gv = ((const float4*)g)[t];
  float4 bv = ((const float4*)b)[t];
  union { unsigned long long u64; u16 h[4]; } o;
  o.h[0] = f2bf(gv.x * (v.x - mean) * inv + bv.x);
  o.h[1] = f2bf(gv.y * (v.y - mean) * inv + bv.y);
  o.h[2] = f2bf(gv.z * (v.z - mean) * inv + bv.z);
  o.h[3] = f2bf(gv.w * (v.w - mean) * inv + bv.w);
  *(unsigned long long*)(outrow + t * 4) = o.u64;
}

// ---------------- prep: all weight transposes + LN1 in ONE launch ----------------
// 16384 blocks: [0,4k) wq/wk/wv/wo transpose; [4k,8k) LN1; [8k,12k) w1; [12k,16k) w2.
__global__ __launch_bounds__(256) void prep(const float* __restrict__ wq,
                                            const float* __restrict__ wk,
                                            const float* __restrict__ wv,
                                            const float* __restrict__ wo,
                                            const float* __restrict__ w1,
                                            const float* __restrict__ w2,
                                            const float* __restrict__ x,
                                            const float* __restrict__ ln1_g,
                                            const float* __restrict__ ln1_b,
                                            u16* __restrict__ wqkvT,  // + woT contiguous
                                            u16* __restrict__ w1T,
                                            u16* __restrict__ w2T,
                                            u16* __restrict__ hout) {
  const int bid = blockIdx.x;
  const int part = bid >> 12;
  const int local = bid & 4095;
  const int t = threadIdx.x;
  if (part == 1) {
    float4 v = ((const float4*)(x + (long)local * 1024))[t];
    ln_core(v, ln1_g, ln1_b, t, hout + (long)local * 1024);
    return;
  }
  __shared__ float tile[32][33];
  const float* src; u16* dst; int C, R, bx, by;
  if (part == 0) {
    int sub = local >> 10;
    src = sub == 0 ? wq : (sub == 1 ? wk : (sub == 2 ? wv : wo));
    dst = wqkvT + (long)sub * 1024 * 1024;
    C = 1024; R = 1024; bx = local & 31; by = (local >> 5) & 31;
  } else if (part == 2) {
    src = w1; dst = w1T; C = 4096; R = 1024; bx = local & 127; by = local >> 7;
  } else {
    src = w2; dst = w2T; C = 1024; R = 4096; bx = local & 31; by = local >> 5;
  }
  int c0 = bx * 32, r0 = by * 32;
  int tx = t & 31, ty = t >> 5;
#pragma unroll
  for (int i = 0; i < 32; i += 8)
    tile[ty + i][tx] = src[(long)(r0 + ty + i) * C + c0 + tx];
  __syncthreads();
#pragma unroll
  for (int i = 0; i < 32; i += 8)
    dst[(long)(c0 + ty + i) * R + r0 + tx] = f2bf(tile[tx][ty + i]);
}

// y = x + bres + P0 + P1 (WO split-K2 reduce); write y fp32 and LN2(y) bf16.
__global__ __launch_bounds__(256) void ln_fuse(const float* __restrict__ x,
                                               const float* __restrict__ bres,
                                               const u16* __restrict__ p0,
                                               const u16* __restrict__ p1,
                                               const float* __restrict__ g,
                                               const float* __restrict__ b,
                                               float* __restrict__ yout,
                                               u16* __restrict__ hout) {
  int row = blockIdx.x, t = threadIdx.x;
  long base = (long)row * 1024;
  float4 xv = ((const float4*)(x + base))[t];
  float4 bo = ((const float4*)bres)[t];
  ushort4 a = ((const ushort4*)(p0 + base))[t];
  ushort4 c = ((const ushort4*)(p1 + base))[t];
  float4 y;
  y.x = xv.x + bo.x + bf2f(a.x) + bf2f(c.x);
  y.y = xv.y + bo.y + bf2f(a.y) + bf2f(c.y);
  y.z = xv.z + bo.z + bf2f(a.z) + bf2f(c.z);
  y.w = xv.w + bo.w + bf2f(a.w) + bf2f(c.w);
  ((float4*)(yout + base))[t] = y;
  ln_core(y, g, b, t, hout + base);
}

// ---------------- bf16 GEMM: C = A(MxK) @ Bt(NxK)^T, templated epilogue ----------------
// (m97-style 128^2 structure; still used for QKV scatter + WO split-K.)
// MODE 0: QKV scatter (+bias; q *= 0.125*log2e; q/k direct, v via LDS transpose -> (bh,d,s))
// MODE 1: bf16 partial store; pointer per z: z0->outp, z1->q_out
template <int MODE>
__global__ __launch_bounds__(256) void gemm_bt(const u16* __restrict__ A,
                                               const u16* __restrict__ Bt, int M, int N, int K,
                                               void* __restrict__ outp,
                                               const float* __restrict__ bias0,
                                               const float* __restrict__ bias1,
                                               const float* __restrict__ bias2,
                                               u16* __restrict__ q_out, u16* __restrict__ k_out,
                                               u16* __restrict__ v_out) {
  __shared__ __align__(16) u16 lds[17408];  // A: [0,8192) B: [8192,16384); epi: 128x136
  u16* ldsA = lds;
  u16* ldsB = lds + 8192;
  const int tid = threadIdx.x;
  const int wave = tid >> 6, lane = tid & 63;
  const int lane16 = lane & 15, quad = lane >> 4;
  const int wm = (wave >> 1) * 64, wn = (wave & 1) * 64;
  const long m0 = (long)blockIdx.y * 128;
  const long n0 = (long)blockIdx.x * 128;
  const int kLen = K / gridDim.z;
  const int kBeg = blockIdx.z * kLen;

  const f32x4 fzero = {0.f, 0.f, 0.f, 0.f};
  f32x4 acc[4][4];
#pragma unroll
  for (int i = 0; i < 4; ++i)
#pragma unroll
    for (int j = 0; j < 4; ++j) acc[i][j] = fzero;

  for (int k0 = kBeg; k0 < kBeg + kLen; k0 += 64) {
    stage128x64(A, m0, k0, K, ldsA, wave, lane);
    stage128x64(Bt, n0, k0, K, ldsB, wave, lane);
    __syncthreads();
#pragma unroll
    for (int kk = 0; kk < 2; ++kk) {
      bf16x8 af[4], bfr[4];
#pragma unroll
      for (int i = 0; i < 4; ++i) {
        int row = wm + i * 16 + lane16;
        int c = (kk * 4 + quad) ^ (row & 7);
        af[i] = *(const bf16x8*)(ldsA + row * 64 + c * 8);
      }
#pragma unroll
      for (int j = 0; j < 4; ++j) {
        int row = wn + j * 16 + lane16;
        int c = (kk * 4 + quad) ^ (row & 7);
        bfr[j] = *(const bf16x8*)(ldsB + row * 64 + c * 8);
      }
#pragma unroll
      for (int i = 0; i < 4; ++i)
#pragma unroll
        for (int j = 0; j < 4; ++j)
          acc[i][j] = __builtin_amdgcn_mfma_f32_16x16x32_bf16(af[i], bfr[j], acc[i][j], 0, 0, 0);
    }
    __syncthreads();
  }

  if (MODE == 0 && (int)(n0 >> 10) == 2) {
    // V path: bias + transpose via LDS, then 128B-contiguous stores to (bh,d,s).
#pragma unroll
    for (int j = 0; j < 4; ++j) {
      int lcol = wn + j * 16 + lane16;
      float bvj = bias2[(int)(n0 - 2048) + lcol];
#pragma unroll
      for (int i = 0; i < 4; ++i)
#pragma unroll
        for (int r = 0; r < 4; ++r) {
          int lrow = wm + i * 16 + quad * 4 + r;
          lds[lcol * 136 + lrow] = f2bf(acc[i][j][r] + bvj);
        }
    }
    __syncthreads();
    int lcol = tid >> 1, seg = tid & 1;
    int cc = (int)(n0 - 2048) + lcol;
    int head = cc >> 6, d = cc & 63;
    int bI = (int)(m0 >> 11), s0 = (int)(m0 & 2047);
    u16* dst = v_out + ((long)(bI * 16 + head) * 64 + d) * 2048 + s0 + seg * 64;
    const u16* s = lds + lcol * 136 + seg * 64;
#pragma unroll
    for (int c2 = 0; c2 < 8; ++c2) ((uint4*)dst)[c2] = ((const uint4*)s)[c2];
    return;
  }

  u16* pp = nullptr;
  if (MODE == 1) pp = blockIdx.z == 0 ? (u16*)outp : q_out;

#pragma unroll
  for (int j = 0; j < 4; ++j) {
    int col = (int)n0 + wn + j * 16 + lane16;
#pragma unroll
    for (int i = 0; i < 4; ++i) {
#pragma unroll
      for (int r = 0; r < 4; ++r) {
        int row = (int)m0 + wm + i * 16 + quad * 4 + r;
        float val = acc[i][j][r];
        if (MODE == 0) {
          int which = col >> 10, cc = col & 1023;
          float vv = val + (which == 0 ? bias0[cc] : bias1[cc]);
          int bb = row >> 11, sS = row & 2047, head = cc >> 6, d = cc & 63;
          long bh = (long)bb * 16 + head;
          if (which == 0) {
            q_out[(bh * 2048 + sS) * 64 + d] = f2bf(vv * 0.18033688f);  // 1/8 * log2(e)
          } else {
            k_out[(bh * 2048 + sS) * 64 + d] = f2bf(vv);
          }
        } else if (MODE == 1) {
          pp[(long)row * N + col] = f2bf(val);
        }
      }
    }
  }
}

// ================= 256^2 8-phase GEMM (T2 swizzle + T3/T4 counted vmcnt + T5 setprio) =======
// C = A(MxK) @ Bt(NxK)^T. BM=BN=256, BK=64, 512 threads = 8 waves (2 wr x 4 wc),
// per-wave 128x64 output => acc[8][4]. LDS 128 KiB: A dbuf [0,32K) u16, B dbuf [32K,64K).
// Per K-tile: 4 phases, each = {ds_read subtile; stage 1 half-tile; s_barrier; lgkmcnt(0);
// setprio(1); 16 MFMA; setprio(0); s_barrier}. Raw s_barrier only (NEVER __syncthreads: it
// drains vmcnt(0) and kills the pipeline). Half-issue order per tile t:
//   ph1: B.h1(t+1)  (B halves of t-1's parity die after its ph2)
//   ph2: A.h1(t+1)  (A halves die after ph3)
//   ph3: B.h0(t+2)  (overwrites own buffer's B.h0 -- reads retired at ph2 barrier)
//   ph4: A.h0(t+2)  (reads retired at ph3 barrier)
// vmcnt(4) once per tile, at ph4 BEFORE the trailing barrier: 12 loads outstanding/thread,
// oldest 8 = all 4 halves of tile t+1 => landed block-wide after the barrier. Requires nT>=2.
// MODE 2: out bf16 = relu(acc + bias[col]).  MODE 1: fp32 unsafeAtomicAdd into outp
// (split-K accumulate; z==0 also adds bias) -- avoids 16M-u16 partial buffers.
template <int MODE>
__global__ __launch_bounds__(512, 1) void gemm8(const u16* __restrict__ A,
                                                const u16* __restrict__ Bt, int M, int N, int K,
                                                void* __restrict__ outp,
                                                const float* __restrict__ bias) {
  __shared__ __align__(16) u16 lds[65536];  // 128 KiB (gfx950 LDS = 160 KiB/WG)
  (void)M;
  const int tid = threadIdx.x;
  const int wave = tid >> 6, lane = tid & 63;
  const int lane16 = lane & 15, quad = lane >> 4;
  const int wr = wave >> 2, wc = wave & 3;
  const long m0 = (long)blockIdx.y * 256;
  const long n0 = (long)blockIdx.x * 256;
  const int kLen = K / gridDim.z;
  const int kBeg = blockIdx.z * kLen;
  const int nT = kLen >> 6;

  u16* const ldsA = lds;
  u16* const ldsB = lds + 32768;

  const f32x4 fzero = {0.f, 0.f, 0.f, 0.f};
  f32x4 acc[8][4];
#pragma unroll
  for (int m = 0; m < 8; ++m)
#pragma unroll
    for (int n = 0; n < 4; ++n) acc[m][n] = fzero;

  // prologue: tile0 {Bh0,Ah0,Bh1,Ah1} + tile1 {Bh0,Ah0} -- ages match steady state
  stage_half512(Bt, n0,       kBeg,      K, ldsB,         wave, lane);
  stage_half512(A,  m0,       kBeg,      K, ldsA,         wave, lane);
  stage_half512(Bt, n0 + 128, kBeg,      K, ldsB + 8192,  wave, lane);
  stage_half512(A,  m0 + 128, kBeg,      K, ldsA + 8192,  wave, lane);
  stage_half512(Bt, n0,       kBeg + 64, K, ldsB + 16384, wave, lane);
  stage_half512(A,  m0,       kBeg + 64, K, ldsA + 16384, wave, lane);
  asm volatile("s_waitcnt vmcnt(4)" ::: "memory");
  asm volatile("s_barrier" ::: "memory");

  for (int t = 0; t < nT; ++t) {
    u16* const aB = ldsA + (t & 1) * 16384;
    u16* const bB = ldsB + (t & 1) * 16384;
    u16* const aN1 = ldsA + ((t + 1) & 1) * 16384;
    u16* const bN1 = ldsB + ((t + 1) & 1) * 16384;
    const int k1 = kBeg + (t + 1 < nT ? t + 1 : nT - 1) * 64;  // clamped: stray loads land in
    const int k2 = kBeg + (t + 2 < nT ? t + 2 : nT - 1) * 64;  // never-again-read halves

    bf16x8 af[4][2], bf01[2][2], bf23[2][2];

    // -------- phase 1: read A[m0-3], B[n0-1]; stage B.h1(t+1); mfma (m0-3)x(n0-1)
#pragma unroll
    for (int m = 0; m < 4; ++m) {
      const int row = wr * 128 + m * 16 + lane16;
#pragma unroll
      for (int kk = 0; kk < 2; ++kk)
        af[m][kk] = *(const bf16x8*)(aB + row * 64 + (((kk * 4 + quad) ^ (row & 7)) << 3));
    }
#pragma unroll
    for (int n = 0; n < 2; ++n) {
      const int row = wc * 64 + n * 16 + lane16;
#pragma unroll
      for (int kk = 0; kk < 2; ++kk)
        bf01[n][kk] = *(const bf16x8*)(bB + row * 64 + (((kk * 4 + quad) ^ (row & 7)) << 3));
    }
    stage_half512(Bt, n0 + 128, k1, K, bN1 + 8192, wave, lane);
    asm volatile("s_barrier" ::: "memory");
    asm volatile("s_waitcnt lgkmcnt(0)" ::: "memory");
    __builtin_amdgcn_sched_barrier(0);
    __builtin_amdgcn_s_setprio(1);
#pragma unroll
    for (int m = 0; m < 4; ++m)
#pragma unroll
      for (int n = 0; n < 2; ++n) {
        acc[m][n] = __builtin_amdgcn_mfma_f32_16x16x32_bf16(af[m][0], bf01[n][0], acc[m][n], 0, 0, 0);
        acc[m][n] = __builtin_amdgcn_mfma_f32_16x16x32_bf16(af[m][1], bf01[n][1], acc[m][n], 0, 0, 0);
      }
    __builtin_amdgcn_s_setprio(0);
    asm volatile("s_barrier" ::: "memory");

    // -------- phase 2: read B[n2-3]; stage A.h1(t+1); mfma (m0-3)x(n2-3)
#pragma unroll
    for (int n = 0; n < 2; ++n) {
      const int row = wc * 64 + (n + 2) * 16 + lane16;
#pragma unroll
      for (int kk = 0; kk < 2; ++kk)
        bf23[n][kk] = *(const bf16x8*)(bB + row * 64 + (((kk * 4 + quad) ^ (row & 7)) << 3));
    }
    stage_half512(A, m0 + 128, k1, K, aN1 + 8192, wave, lane);
    asm volatile("s_barrier" ::: "memory");
    asm volatile("s_waitcnt lgkmcnt(0)" ::: "memory");
    __builtin_amdgcn_sched_barrier(0);
    __builtin_amdgcn_s_setprio(1);
#pragma unroll
    for (int m = 0; m < 4; ++m)
#pragma unroll
      for (int n = 0; n < 2; ++n) {
        acc[m][n + 2] = __builtin_amdgcn_mfma_f32_16x16x32_bf16(af[m][0], bf23[n][0], acc[m][n + 2], 0, 0, 0);
        acc[m][n + 2] = __builtin_amdgcn_mfma_f32_16x16x32_bf16(af[m][1], bf23[n][1], acc[m][n + 2], 0, 0, 0);
      }
    __builtin_amdgcn_s_setprio(0);
    asm volatile("s_barrier" ::: "memory");

    // -------- phase 3: read A[m4-7]; stage B.h0(t+2); mfma (m4-7)x(n2-3)
#pragma unroll
    for (int m = 0; m < 4; ++m) {
      const int row = wr * 128 + (m + 4) * 16 + lane16;
#pragma unroll
      for (int kk = 0; kk < 2; ++kk)
        af[m][kk] = *(const bf16x8*)(aB + row * 64 + (((kk * 4 + quad) ^ (row & 7)) << 3));
    }
    stage_half512(Bt, n0, k2, K, bB, wave, lane);
    asm volatile("s_barrier" ::: "memory");
    asm volatile("s_waitcnt lgkmcnt(0)" ::: "memory");
    __builtin_amdgcn_sched_barrier(0);
    __builtin_amdgcn_s_setprio(1);
#pragma unroll
    for (int m = 0; m < 4; ++m)
#pragma unroll
      for (int n = 0; n < 2; ++n) {
        acc[m + 4][n + 2] = __builtin_amdgcn_mfma_f32_16x16x32_bf16(af[m][0], bf23[n][0], acc[m + 4][n + 2], 0, 0, 0);
        acc[m + 4][n + 2] = __builtin_amdgcn_mfma_f32_16x16x32_bf16(af[m][1], bf23[n][1], acc[m + 4][n + 2], 0, 0, 0);
      }
    __builtin_amdgcn_s_setprio(0);
    asm volatile("s_barrier" ::: "memory");

    // -------- phase 4: stage A.h0(t+2); mfma (m4-7)x(n0-1); vmcnt(4) BEFORE barrier
    stage_half512(A, m0, k2, K, aB, wave, lane);
    asm volatile("s_barrier" ::: "memory");
    __builtin_amdgcn_s_setprio(1);
#pragma unroll
    for (int m = 0; m < 4; ++m)
#pragma unroll
      for (int n = 0; n < 2; ++n) {
        acc[m + 4][n] = __builtin_amdgcn_mfma_f32_16x16x32_bf16(af[m][0], bf01[n][0], acc[m + 4][n], 0, 0, 0);
        acc[m + 4][n] = __builtin_amdgcn_mfma_f32_16x16x32_bf16(af[m][1], bf01[n][1], acc[m + 4][n], 0, 0, 0);
      }
    __builtin_amdgcn_s_setprio(0);
    asm volatile("s_waitcnt vmcnt(4)" ::: "memory");
    asm volatile("s_barrier" ::: "memory");
  }

  // drain stray clamped prefetches before LDS dealloc / kernel end
  asm volatile("s_waitcnt vmcnt(0)" ::: "memory");

  if (MODE == 2) {
    u16* op = (u16*)outp;
#pragma unroll
    for (int n = 0; n < 4; ++n) {
      const int col = (int)n0 + wc * 64 + n * 16 + lane16;
      const float bv = bias[col];
#pragma unroll
      for (int m = 0; m < 8; ++m) {
        const long rbase = ((long)m0 + wr * 128 + m * 16 + quad * 4) * N + col;
#pragma unroll
        for (int r = 0; r < 4; ++r)
          op[rbase + (long)r * N] = f2bf(fmaxf(acc[m][n][r] + bv, 0.0f));
      }
    }
  } else {
    float* op = (float*)outp;
    const bool z0 = (blockIdx.z == 0);
#pragma unroll
    for (int n = 0; n < 4; ++n) {
      const int col = (int)n0 + wc * 64 + n * 16 + lane16;
      const float bv = z0 ? bias[col] : 0.0f;
#pragma unroll
      for (int m = 0; m < 8; ++m) {
        const long rbase = ((long)m0 + wr * 128 + m * 16 + quad * 4) * N + col;
#pragma unroll
        for (int r = 0; r < 4; ++r)
          unsafeAtomicAdd(op + rbase + (long)r * N, acc[m][n][r] + bv);
      }
    }
  }
}

// -------- flash attention: 128-q blocks, 32 q/wave (best measured config: R5 layout) --------
// grid (16 q-tiles, 32 bh), XCD-remapped so all 16 q-tiles of one bh share an XCD L2.
// S^T = mfma(A=K,B=Q): lane holds 4 consecutive keys -> exp2 + v_perm pack -> ds_write_b64.
// P of waves 0/1 aliases ldsK (barrier between S-compute and pack); waves 2/3 dedicated.
// LDS ~50KB -> 3 blocks/CU. Mask folded post-MFMA only on !allv tiles (never for all-ones).
#define FA_C0 28.854239f  // 20 * log2(e) safety offset; scores |S|<~4 << 20
__global__ __launch_bounds__(256) void flash_attn(const u16* __restrict__ q,
                                                  const u16* __restrict__ k,
                                                  const u16* __restrict__ v,
                                                  const int* __restrict__ mask,
                                                  u16* __restrict__ ctx) {
  // XCD-aware remap: flat id -> (bh, qtile) s.t. same bh stays on one XCD (id&7).
  const int fid = blockIdx.y * 16 + blockIdx.x;
  const int xcd = fid & 7, slot = fid >> 3;
  const int bh = xcd * 4 + (slot >> 4);
  const int q0 = (slot & 15) * 128;
  const int b = bh >> 4, h = bh & 15;
  const int tid = threadIdx.x;
  const int wave = tid >> 6, lane = tid & 63;
  const int lane16 = lane & 15, quad = lane >> 4;

  const u16* qp = q + (long)bh * 2048 * 64;
  const u16* kp = k + (long)bh * 2048 * 64;
  const u16* vp = v + (long)bh * 64 * 2048;
  const int* mp = mask + b * 2048;

  __shared__ __align__(16) u16 ldsK[128 * 64];    // 16KB; P of waves 0/1 aliases
  __shared__ __align__(16) u16 ldsVT[64 * 128];   // 16KB
  __shared__ __align__(16) u16 ldsP23[2 * 4096];  // 16KB; P of waves 2/3
  __shared__ __align__(16) float ldsMask[128];
  __shared__ int ldsFlag[2];
  u16* myP = (wave < 2) ? (ldsK + wave * 4096) : (ldsP23 + (wave - 2) * 4096);

  bf16x8 qf[2][2];
#pragma unroll
  for (int g = 0; g < 2; ++g) {
    const long qrow = q0 + wave * 32 + g * 16 + lane16;
    qf[g][0] = *(const bf16x8*)(qp + qrow * 64 + quad * 8);
    qf[g][1] = *(const bf16x8*)(qp + qrow * 64 + 32 + quad * 8);
  }

  const f32x4 fzero = {0.f, 0.f, 0.f, 0.f};
  const f32x4 cC0 = {-FA_C0, -FA_C0, -FA_C0, -FA_C0};
  float l_loc[2] = {0.f, 0.f};
  f32x4 o_acc[2][4];
#pragma unroll
  for (int g = 0; g < 2; ++g)
#pragma unroll
    for (int j = 0; j < 4; ++j) o_acc[g][j] = fzero;

  const int xorm = (lane16 & 7) << 2;  // P chunk swizzle per q-row
  u16* const pw0 = myP + lane16 * 128;         // P write base, g=0
  u16* const pw1 = myP + (16 + lane16) * 128;  // g=1

  for (int kt = 0; kt < 2048; kt += 128) {
    stage128x64(kp, kt, 0, 64, ldsK, wave, lane);
    stage64x128(vp, kt, 2048, ldsVT, wave, lane);
    if (tid < 128) {
      int mv = mp[kt + tid];
      ldsMask[tid] = (mv == 0) ? -1.0e9f : 0.0f;
      unsigned long long bal = __ballot(mv != 0);
      if ((tid & 63) == 0) ldsFlag[tid >> 6] = (bal == ~0ull) ? 1 : 0;
    }
    __syncthreads();
    const bool allv = (ldsFlag[0] & ldsFlag[1]) != 0;

    // S^T = K @ Q^T  (128 keys x 32 q per wave); C-init = -C0
    f32x4 s_acc[8][2];
#pragma unroll
    for (int j = 0; j < 8; ++j) {
      int row = j * 16 + lane16;
      int c0i = quad ^ (row & 7);
      int c1i = (4 + quad) ^ (row & 7);
      bf16x8 kf0 = *(const bf16x8*)(ldsK + row * 64 + c0i * 8);
      bf16x8 kf1 = *(const bf16x8*)(ldsK + row * 64 + c1i * 8);
#pragma unroll
      for (int g = 0; g < 2; ++g) {
        f32x4 sa = __builtin_amdgcn_mfma_f32_16x16x32_bf16(kf0, qf[g][0], cC0, 0, 0, 0);
        sa = __builtin_amdgcn_mfma_f32_16x16x32_bf16(kf1, qf[g][1], sa, 0, 0, 0);
        s_acc[j][g] = sa;
      }
    }
    __syncthreads();  // all waves' K reads done; waves 0/1 may overwrite ldsK with P

    // p = 2^s (mask deferred: only on !allv tiles): pack 2x v_perm + 1 ds_write_b64
#pragma unroll
    for (int j = 0; j < 8; ++j) {
      int cw = ((4 * j + quad) ^ xorm) * 4;
#pragma unroll
      for (int g = 0; g < 2; ++g) {
        f32x4 sa = s_acc[j][g];
        if (!allv) {
          f32x4 mk = *(const f32x4*)(ldsMask + j * 16 + quad * 4);
          sa = sa + mk;
        }
        float p0 = __builtin_exp2f(sa[0]);
        float p1 = __builtin_exp2f(sa[1]);
        float p2 = __builtin_exp2f(sa[2]);
        float p3 = __builtin_exp2f(sa[3]);
        l_loc[g] += (p0 + p1) + (p2 + p3);
        uint2 pk;
        pk.x = __builtin_amdgcn_perm(fbits(p1), fbits(p0), 0x07060302u);  // bf16 trunc pair
        pk.y = __builtin_amdgcn_perm(fbits(p3), fbits(p2), 0x07060302u);
        *(uint2*)((g ? pw1 : pw0) + cw) = pk;
      }
    }
    // O += P @ V (myP wave-private; in-wave write->read ordering only)
#pragma unroll
    for (int kk = 0; kk < 4; ++kk) {
      int cr = ((8 * kk + 2 * quad) ^ xorm) * 4;
      bf16x8 pf0 = *(const bf16x8*)(pw0 + cr);
      bf16x8 pf1 = *(const bf16x8*)(pw1 + cr);
#pragma unroll
      for (int jj = 0; jj < 4; ++jj) {
        int row = jj * 16 + lane16;
        int cv = (kk * 4 + quad) ^ (row & 15);
        bf16x8 vf = *(const bf16x8*)(ldsVT + row * 128 + cv * 8);
        o_acc[0][jj] = __builtin_amdgcn_mfma_f32_16x16x32_bf16(pf0, vf, o_acc[0][jj], 0, 0, 0);
        o_acc[1][jj] = __builtin_amdgcn_mfma_f32_16x16x32_bf16(pf1, vf, o_acc[1][jj], 0, 0, 0);
      }
    }
    __syncthreads();  // P(aliased)/VT reads done before next stage overwrites
  }

  // l: sum across quads; broadcast per-o-row inverse
  float lr[2][4];
#pragma unroll
  for (int g = 0; g < 2; ++g) {
    float l = l_loc[g];
#pragma unroll
    for (int off = 16; off < 64; off <<= 1) l += __shfl_xor(l, off);
    float linv = 1.0f / l;  // valid for q = lane16 in every quad
#pragma unroll
    for (int r = 0; r < 4; ++r) lr[g][r] = __shfl(linv, quad * 4 + r);
  }

#pragma unroll
  for (int g = 0; g < 2; ++g)
#pragma unroll
    for (int jj = 0; jj < 4; ++jj)
#pragma unroll
      for (int r = 0; r < 4; ++r) {
        int sg = q0 + wave * 32 + g * 16 + quad * 4 + r;
        int d = jj * 16 + lane16;
        float val = o_acc[g][jj][r] * lr[g][r];
        ctx[((long)b * 2048 + sg) * 1024 + h * 64 + d] = f2bf(val);
      }
}

extern "C" void kernel_launch(void* const* d_in, const int* in_sizes, int n_in, void* d_out,
                              int out_size, void* d_ws, size_t ws_size, hipStream_t stream) {
  (void)in_sizes; (void)n_in; (void)out_size; (void)ws_size;
  const float* x  = (const float*)d_in[0];
  const int* mask = (const int*)d_in[1];
  const float* wq = (const float*)d_in[2];
  const float* wk = (const float*)d_in[3];
  const float* wv = (const float*)d_in[4];
  const float* wo = (const float*)d_in[5];
  const float* bq = (const float*)d_in[6];
  const float* bk = (const float*)d_in[7];
  const float* bv = (const float*)d_in[8];
  const float* bo = (const float*)d_in[9];
  const float* w1 = (const float*)d_in[10];
  const float* b1 = (const float*)d_in[11];
  const float* w2 = (const float*)d_in[12];
  const float* b2 = (const float*)d_in[13];
  const float* ln1_g = (const float*)d_in[14];
  const float* ln1_b = (const float*)d_in[15];
  const float* ln2_g = (const float*)d_in[16];
  const float* ln2_b = (const float*)d_in[17];
  float* out = (float*)d_out;

  u16* ws = (u16*)d_ws;
  u16* wqkvT = ws;                      // [0,3M) u16
  u16* woT = wqkvT + 3072 * 1024;       // [3M,4M)
  u16* w1T = woT + 1024 * 1024;         // [4M,8M)
  u16* w2T = w1T + 4096 * 1024;         // [8M,12M)
  u16* h   = w2T + 4096 * 1024;         // [12M,16M)  LN1 out; LN2 out
  u16* qb  = h + 4096 * 1024;           // [16M,20M)  Q; WO partial0
  u16* kb  = qb + 4096 * 1024;          // [20M,24M)  K; WO partial1
  u16* vb  = kb + 4096 * 1024;          // [24M,28M)  V^T
  u16* ctx = vb + 4096 * 1024;          // [28M,32M)
  u16* ffh = qb;                        // [16M,32M)  4096x4096 relu acts (qb..ctx dead)

  // one launch: wq/wk/wv/wo/w1/w2 transposes + LN1
  prep<<<16384, 256, 0, stream>>>(wq, wk, wv, wo, w1, w2, x, ln1_g, ln1_b,
                                  wqkvT, w1T, w2T, h);

  gemm_bt<0><<<dim3(24, 32), 256, 0, stream>>>(h, wqkvT, 4096, 3072, 1024, nullptr, bq, bk, bv,
                                               qb, kb, vb);

  flash_attn<<<dim3(16, 32), 256, 0, stream>>>(qb, kb, vb, mask, ctx);

  // WO: split-K x2, bf16 partials into qb (z0) / kb (z1), both dead after attention
  gemm_bt<1><<<dim3(8, 32, 2), 256, 0, stream>>>(ctx, woT, 4096, 1024, 1024, qb, nullptr,
                                                 nullptr, nullptr, kb, nullptr, nullptr);

  // fused: y = x + bo + P0 + P1 -> out (fp32 residual) and h = LN2(y) bf16
  ln_fuse<<<4096, 256, 0, stream>>>(x, bo, qb, kb, ln2_g, ln2_b, out, h);

  // FFN1: 256^2 8-phase, grid 16x16 = 256 blocks (1/CU), relu+bias epilogue
  gemm8<2><<<dim3(16, 16), 512, 0, stream>>>(h, w1T, 4096, 4096, 1024, ffh, b1);

  // FFN2: 256^2 8-phase, split-K x4 (grid 4x16x4 = 256 blocks), fp32 atomic accumulate
  // into the residual (z==0 adds b2); replaces bf16 partials + final_add.
  gemm8<1><<<dim3(4, 16, 4), 512, 0, stream>>>(ffh, w2T, 4096, 1024, 4096, out, b2);
}

// Round 2
// 355.827 us; speedup vs baseline: 1.0775x; 1.0775x over previous
//
#include <hip/hip_runtime.h>

typedef unsigned short u16;
typedef unsigned int u32;
typedef __attribute__((ext_vector_type(8))) short bf16x8;
typedef __attribute__((ext_vector_type(4))) float f32x4;

__device__ __forceinline__ u16 f2bf(float f) {
  union { float f; unsigned int u; } x;
  x.f = f;
  unsigned int r = x.u + 0x7fffu + ((x.u >> 16) & 1u);
  return (u16)(r >> 16);
}

__device__ __forceinline__ float bf2f(u16 v) {
  union { unsigned int u; float f; } x;
  x.u = ((unsigned int)v) << 16;
  return x.f;
}

__device__ __forceinline__ u32 fbits(float f) {
  union { float f; u32 u; } x; x.f = f; return x.u;
}

__device__ __forceinline__ void async16(const u16* g, u16* l) {
  __builtin_amdgcn_global_load_lds((const __attribute__((address_space(1))) void*)g,
                                   (__attribute__((address_space(3))) void*)l, 16, 0, 0);
}

// Stage 128 rows x 64 cols bf16 tile (256 threads). LDS slot s: row=s>>3, stored chunk (s&7)
// holds global 16B chunk c = (s&7) ^ (row&7)  (XOR swizzle -> conflict-free b128 reads).
__device__ __forceinline__ void stage128x64(const u16* __restrict__ src, long row0, int k0,
                                            int ld, u16* lds, int wave, int lane) {
#pragma unroll
  for (int r = 0; r < 4; ++r) {
    int s = r * 256 + wave * 64 + lane;
    int row = s >> 3;
    int c = (s & 7) ^ (row & 7);
    async16(src + (row0 + row) * (long)ld + k0 + c * 8, lds + (r * 256 + wave * 64) * 8);
  }
}

// Same 128x64 half-tile staging, but for a 512-thread block (2 issues/thread).
__device__ __forceinline__ void stage_half512(const u16* __restrict__ src, long row0, int k0,
                                              int ld, u16* lbase, int wave, int lane) {
#pragma unroll
  for (int r = 0; r < 2; ++r) {
    int s = r * 512 + wave * 64 + lane;
    int row = s >> 3;
    int c = (s & 7) ^ (row & 7);
    async16(src + (row0 + row) * (long)ld + k0 + c * 8, lbase + (r * 512 + wave * 64) * 8);
  }
}

// Stage 64 rows x 128 cols (V^T tile): 16 chunks/row, swizzle c = (s&15)^(row&15).
__device__ __forceinline__ void stage64x128(const u16* __restrict__ src, int col0, int ld,
                                            u16* lds, int wave, int lane) {
#pragma unroll
  for (int r = 0; r < 4; ++r) {
    int s = r * 256 + wave * 64 + lane;
    int row = s >> 4;
    int c = (s & 15) ^ (row & 15);
    async16(src + (long)row * ld + col0 + c * 8, lds + (r * 256 + wave * 64) * 8);
  }
}

// ---------------- LayerNorm core (torch-style: unbiased std, /(std+eps)) ----------------
__device__ __forceinline__ void ln_core(float4 v, const float* g, const float* b, int t,
                                        u16* outrow) {
  float s = v.x + v.y + v.z + v.w;
  float ss = v.x * v.x + v.y * v.y + v.z * v.z + v.w * v.w;
#pragma unroll
  for (int off = 32; off; off >>= 1) {
    s += __shfl_xor(s, off);
    ss += __shfl_xor(ss, off);
  }
  __shared__ float red[8];
  int wave = t >> 6, lane = t & 63;
  if (lane == 0) { red[wave] = s; red[wave + 4] = ss; }
  __syncthreads();
  float tot = red[0] + red[1] + red[2] + red[3];
  float tots = red[4] + red[5] + red[6] + red[7];
  float mean = tot * (1.0f / 1024.0f);
  float var = (tots - 1024.0f * mean * mean) * (1.0f / 1023.0f);
  var = fmaxf(var, 0.0f);
  float inv = 1.0f / (sqrtf(var) + 1e-6f);
  float4 gv = ((const float4*)g)[t];
  float4 bv = ((const float4*)b)[t];
  union { unsigned long long u64; u16 h[4]; } o;
  o.h[0] = f2bf(gv.x * (v.x - mean) * inv + bv.x);
  o.h[1] = f2bf(gv.y * (v.y - mean) * inv + bv.y);
  o.h[2] = f2bf(gv.z * (v.z - mean) * inv + bv.z);
  o.h[3] = f2bf(gv.w * (v.w - mean) * inv + bv.w);
  *(unsigned long long*)(outrow + t * 4) = o.u64;
}

// ---------------- prep: all weight transposes + LN1 in ONE launch ----------------
// 16384 blocks: [0,4k) wq/wk/wv/wo transpose; [4k,8k) LN1; [8k,12k) w1; [12k,16k) w2.
__global__ __launch_bounds__(256) void prep(const float* __restrict__ wq,
                                            const float* __restrict__ wk,
                                            const float* __restrict__ wv,
                                            const float* __restrict__ wo,
                                            const float* __restrict__ w1,
                                            const float* __restrict__ w2,
                                            const float* __restrict__ x,
                                            const float* __restrict__ ln1_g,
                                            const float* __restrict__ ln1_b,
                                            u16* __restrict__ wqkvT,  // + woT contiguous
                                            u16* __restrict__ w1T,
                                            u16* __restrict__ w2T,
                                            u16* __restrict__ hout) {
  const int bid = blockIdx.x;
  const int part = bid >> 12;
  const int local = bid & 4095;
  const int t = threadIdx.x;
  if (part == 1) {
    float4 v = ((const float4*)(x + (long)local * 1024))[t];
    ln_core(v, ln1_g, ln1_b, t, hout + (long)local * 1024);
    return;
  }
  __shared__ float tile[32][33];
  const float* src; u16* dst; int C, R, bx, by;
  if (part == 0) {
    int sub = local >> 10;
    src = sub == 0 ? wq : (sub == 1 ? wk : (sub == 2 ? wv : wo));
    dst = wqkvT + (long)sub * 1024 * 1024;
    C = 1024; R = 1024; bx = local & 31; by = (local >> 5) & 31;
  } else if (part == 2) {
    src = w1; dst = w1T; C = 4096; R = 1024; bx = local & 127; by = local >> 7;
  } else {
    src = w2; dst = w2T; C = 1024; R = 4096; bx = local & 31; by = local >> 5;
  }
  int c0 = bx * 32, r0 = by * 32;
  int tx = t & 31, ty = t >> 5;
#pragma unroll
  for (int i = 0; i < 32; i += 8)
    tile[ty + i][tx] = src[(long)(r0 + ty + i) * C + c0 + tx];
  __syncthreads();
#pragma unroll
  for (int i = 0; i < 32; i += 8)
    dst[(long)(c0 + ty + i) * R + r0 + tx] = f2bf(tile[tx][ty + i]);
}

// y = x + bres + P0 + P1 (WO split-K2 reduce); write y fp32 and LN2(y) bf16.
__global__ __launch_bounds__(256) void ln_fuse(const float* __restrict__ x,
                                               const float* __restrict__ bres,
                                               const u16* __restrict__ p0,
                                               const u16* __restrict__ p1,
                                               const float* __restrict__ g,
                                               const float* __restrict__ b,
                                               float* __restrict__ yout,
                                               u16* __restrict__ hout) {
  int row = blockIdx.x, t = threadIdx.x;
  long base = (long)row * 1024;
  float4 xv = ((const float4*)(x + base))[t];
  float4 bo = ((const float4*)bres)[t];
  ushort4 a = ((const ushort4*)(p0 + base))[t];
  ushort4 c = ((const ushort4*)(p1 + base))[t];
  float4 y;
  y.x = xv.x + bo.x + bf2f(a.x) + bf2f(c.x);
  y.y = xv.y + bo.y + bf2f(a.y) + bf2f(c.y);
  y.z = xv.z + bo.z + bf2f(a.z) + bf2f(c.z);
  y.w = xv.w + bo.w + bf2f(a.w) + bf2f(c.w);
  ((float4*)(yout + base))[t] = y;
  ln_core(y, g, b, t, hout + base);
}

// out += b2 + P0 + P1 + P2 + P3 (FFN2 split-K4 reduce + bias, in-place on residual)
__global__ __launch_bounds__(256) void final_add(float* __restrict__ out,
                                                 const float* __restrict__ b2,
                                                 const u16* __restrict__ p0,
                                                 const u16* __restrict__ p1,
                                                 const u16* __restrict__ p2,
                                                 const u16* __restrict__ p3) {
  int row = blockIdx.x, t = threadIdx.x;
  long base = (long)row * 1024;
  float4 o = ((float4*)(out + base))[t];
  float4 bb = ((const float4*)b2)[t];
  ushort4 a = ((const ushort4*)(p0 + base))[t];
  ushort4 c = ((const ushort4*)(p1 + base))[t];
  ushort4 d = ((const ushort4*)(p2 + base))[t];
  ushort4 e = ((const ushort4*)(p3 + base))[t];
  o.x += bb.x + (bf2f(a.x) + bf2f(c.x)) + (bf2f(d.x) + bf2f(e.x));
  o.y += bb.y + (bf2f(a.y) + bf2f(c.y)) + (bf2f(d.y) + bf2f(e.y));
  o.z += bb.z + (bf2f(a.z) + bf2f(c.z)) + (bf2f(d.z) + bf2f(e.z));
  o.w += bb.w + (bf2f(a.w) + bf2f(c.w)) + (bf2f(d.w) + bf2f(e.w));
  ((float4*)(out + base))[t] = o;
}

// ---------------- bf16 GEMM: C = A(MxK) @ Bt(NxK)^T, templated epilogue ----------------
// (m97-style 128^2 structure; still used for QKV scatter + WO split-K.)
// MODE 0: QKV scatter (+bias; q *= 0.125*log2e; q/k direct, v via LDS transpose -> (bh,d,s))
// MODE 1: bf16 partial store; pointer per z: z0->outp, z1->q_out
template <int MODE>
__global__ __launch_bounds__(256) void gemm_bt(const u16* __restrict__ A,
                                               const u16* __restrict__ Bt, int M, int N, int K,
                                               void* __restrict__ outp,
                                               const float* __restrict__ bias0,
                                               const float* __restrict__ bias1,
                                               const float* __restrict__ bias2,
                                               u16* __restrict__ q_out, u16* __restrict__ k_out,
                                               u16* __restrict__ v_out) {
  __shared__ __align__(16) u16 lds[17408];  // A: [0,8192) B: [8192,16384); epi: 128x136
  u16* ldsA = lds;
  u16* ldsB = lds + 8192;
  const int tid = threadIdx.x;
  const int wave = tid >> 6, lane = tid & 63;
  const int lane16 = lane & 15, quad = lane >> 4;
  const int wm = (wave >> 1) * 64, wn = (wave & 1) * 64;
  const long m0 = (long)blockIdx.y * 128;
  const long n0 = (long)blockIdx.x * 128;
  const int kLen = K / gridDim.z;
  const int kBeg = blockIdx.z * kLen;

  const f32x4 fzero = {0.f, 0.f, 0.f, 0.f};
  f32x4 acc[4][4];
#pragma unroll
  for (int i = 0; i < 4; ++i)
#pragma unroll
    for (int j = 0; j < 4; ++j) acc[i][j] = fzero;

  for (int k0 = kBeg; k0 < kBeg + kLen; k0 += 64) {
    stage128x64(A, m0, k0, K, ldsA, wave, lane);
    stage128x64(Bt, n0, k0, K, ldsB, wave, lane);
    __syncthreads();
#pragma unroll
    for (int kk = 0; kk < 2; ++kk) {
      bf16x8 af[4], bfr[4];
#pragma unroll
      for (int i = 0; i < 4; ++i) {
        int row = wm + i * 16 + lane16;
        int c = (kk * 4 + quad) ^ (row & 7);
        af[i] = *(const bf16x8*)(ldsA + row * 64 + c * 8);
      }
#pragma unroll
      for (int j = 0; j < 4; ++j) {
        int row = wn + j * 16 + lane16;
        int c = (kk * 4 + quad) ^ (row & 7);
        bfr[j] = *(const bf16x8*)(ldsB + row * 64 + c * 8);
      }
#pragma unroll
      for (int i = 0; i < 4; ++i)
#pragma unroll
        for (int j = 0; j < 4; ++j)
          acc[i][j] = __builtin_amdgcn_mfma_f32_16x16x32_bf16(af[i], bfr[j], acc[i][j], 0, 0, 0);
    }
    __syncthreads();
  }

  if (MODE == 0 && (int)(n0 >> 10) == 2) {
    // V path: bias + transpose via LDS, then 128B-contiguous stores to (bh,d,s).
#pragma unroll
    for (int j = 0; j < 4; ++j) {
      int lcol = wn + j * 16 + lane16;
      float bvj = bias2[(int)(n0 - 2048) + lcol];
#pragma unroll
      for (int i = 0; i < 4; ++i)
#pragma unroll
        for (int r = 0; r < 4; ++r) {
          int lrow = wm + i * 16 + quad * 4 + r;
          lds[lcol * 136 + lrow] = f2bf(acc[i][j][r] + bvj);
        }
    }
    __syncthreads();
    int lcol = tid >> 1, seg = tid & 1;
    int cc = (int)(n0 - 2048) + lcol;
    int head = cc >> 6, d = cc & 63;
    int bI = (int)(m0 >> 11), s0 = (int)(m0 & 2047);
    u16* dst = v_out + ((long)(bI * 16 + head) * 64 + d) * 2048 + s0 + seg * 64;
    const u16* s = lds + lcol * 136 + seg * 64;
#pragma unroll
    for (int c2 = 0; c2 < 8; ++c2) ((uint4*)dst)[c2] = ((const uint4*)s)[c2];
    return;
  }

  u16* pp = nullptr;
  if (MODE == 1) pp = blockIdx.z == 0 ? (u16*)outp : q_out;

#pragma unroll
  for (int j = 0; j < 4; ++j) {
    int col = (int)n0 + wn + j * 16 + lane16;
#pragma unroll
    for (int i = 0; i < 4; ++i) {
#pragma unroll
      for (int r = 0; r < 4; ++r) {
        int row = (int)m0 + wm + i * 16 + quad * 4 + r;
        float val = acc[i][j][r];
        if (MODE == 0) {
          int which = col >> 10, cc = col & 1023;
          float vv = val + (which == 0 ? bias0[cc] : bias1[cc]);
          int bb = row >> 11, sS = row & 2047, head = cc >> 6, d = cc & 63;
          long bh = (long)bb * 16 + head;
          if (which == 0) {
            q_out[(bh * 2048 + sS) * 64 + d] = f2bf(vv * 0.18033688f);  // 1/8 * log2(e)
          } else {
            k_out[(bh * 2048 + sS) * 64 + d] = f2bf(vv);
          }
        } else if (MODE == 1) {
          pp[(long)row * N + col] = f2bf(val);
        }
      }
    }
  }
}

// ============ 256^2 8-phase GEMM, quadrant-rotating schedule (deep prefetch) ============
// C = A(MxK) @ Bt(NxK)^T. BM=BN=256, BK=64, 512 threads = 8 waves. LDS 128 KiB dbuf.
// Each wave computes a slice of ALL FOUR (A-half x B-half) quadrants, one per phase:
//   ph1:(A0,B0) fresh A0+B0   ph2:(A0,B1) fresh B1, reuse A0 regs
//   ph3:(A1,B1) fresh A1      ph4:(A1,B0) reuse A1 + B0 regs (B0 lives ph1->ph4)
// => every LDS region is ds_read in exactly ONE phase, so each half-tile stage is issued
// 6-7 phases before consumption. Per-phase stage (region died previous phase):
//   ph1(t): A.h1(t+1)   ph2(t): A.h0(t+2)   ph3(t): B.h0(t+2)   ph4(t): B.h1(t+2)
// Uniform s_waitcnt vmcnt(10) (cap 5 stages in flight) before EVERY trailing barrier:
// retires exactly one stage/phase in steady state; youngest-required is always >=4.5
// phases (~1000 cyc) old => no HBM-latency stall (the R1 schedule stalled here).
// Raw s_barrier only (never __syncthreads: it drains vmcnt(0)). Requires nT>=2.
// MODE 2: out bf16 = relu(acc + bias[col]).  MODE 1: bf16 partial per z-slice
// (outp + z*4M u16); reduce in final_add (atomics measured 2x worse: R1).
template <int MODE>
__global__ __launch_bounds__(512, 1) void gemm8(const u16* __restrict__ A,
                                                const u16* __restrict__ Bt, int M, int N, int K,
                                                void* __restrict__ outp,
                                                const float* __restrict__ bias) {
  __shared__ __align__(16) u16 lds[65536];  // 128 KiB
  (void)M;
  const int tid = threadIdx.x;
  const int wave = tid >> 6, lane = tid & 63;
  const int lane16 = lane & 15, quad = lane >> 4;
  const int wr2 = wave >> 2, wc2 = wave & 3;  // 2 x 4 wave grid within a quadrant
  const long m0 = (long)blockIdx.y * 256;
  const long n0 = (long)blockIdx.x * 256;
  const int kLen = K / gridDim.z;
  const int kBeg = blockIdx.z * kLen;
  const int nT = kLen >> 6;

  u16* const ldsA = lds;
  u16* const ldsB = lds + 32768;

  const f32x4 fzero = {0.f, 0.f, 0.f, 0.f};
  f32x4 acc[2][2][4][2];  // [qa][qb][m][n]
#pragma unroll
  for (int qa = 0; qa < 2; ++qa)
#pragma unroll
    for (int qb = 0; qb < 2; ++qb)
#pragma unroll
      for (int m = 0; m < 4; ++m)
#pragma unroll
        for (int n = 0; n < 2; ++n) acc[qa][qb][m][n] = fzero;

  // prologue: steady-state issue order [Ah0(0),Bh0(0),Bh1(0),Ah1(0),Ah0(1),Bh0(1),Bh1(1)]
  stage_half512(A,  m0,       kBeg,      K, ldsA,                 wave, lane);
  stage_half512(Bt, n0,       kBeg,      K, ldsB,                 wave, lane);
  stage_half512(Bt, n0 + 128, kBeg,      K, ldsB + 8192,          wave, lane);
  stage_half512(A,  m0 + 128, kBeg,      K, ldsA + 8192,          wave, lane);
  stage_half512(A,  m0,       kBeg + 64, K, ldsA + 16384,         wave, lane);
  stage_half512(Bt, n0,       kBeg + 64, K, ldsB + 16384,         wave, lane);
  stage_half512(Bt, n0 + 128, kBeg + 64, K, ldsB + 16384 + 8192,  wave, lane);
  asm volatile("s_waitcnt vmcnt(10)" ::: "memory");  // retire Ah0(0),Bh0(0)
  asm volatile("s_barrier" ::: "memory");

  for (int t = 0; t < nT; ++t) {
    u16* const aB = ldsA + (t & 1) * 16384;
    u16* const bB = ldsB + (t & 1) * 16384;
    u16* const aN1 = ldsA + ((t + 1) & 1) * 16384;
    const int k1 = kBeg + (t + 1 < nT ? t + 1 : nT - 1) * 64;  // clamped strays land in
    const int k2 = kBeg + (t + 2 < nT ? t + 2 : nT - 1) * 64;  // already-dead regions

    bf16x8 af[4][2], b0f[2][2], b1f[2][2];

    // ---- ph1: quadrant (A0,B0); read A0 (8) + B0 (4); stage A.h1(t+1)
#pragma unroll
    for (int m = 0; m < 4; ++m) {
      const int row = wr2 * 64 + m * 16 + lane16;  // A rows 0..127 (h0)
#pragma unroll
      for (int kk = 0; kk < 2; ++kk)
        af[m][kk] = *(const bf16x8*)(aB + row * 64 + (((kk * 4 + quad) ^ (row & 7)) << 3));
    }
#pragma unroll
    for (int n = 0; n < 2; ++n) {
      const int row = wc2 * 32 + n * 16 + lane16;  // B rows 0..127 (h0)
#pragma unroll
      for (int kk = 0; kk < 2; ++kk)
        b0f[n][kk] = *(const bf16x8*)(bB + row * 64 + (((kk * 4 + quad) ^ (row & 7)) << 3));
    }
    stage_half512(A, m0 + 128, k1, K, aN1 + 8192, wave, lane);
    asm volatile("s_barrier" ::: "memory");
    asm volatile("s_waitcnt lgkmcnt(0)" ::: "memory");
    __builtin_amdgcn_sched_barrier(0);
    __builtin_amdgcn_s_setprio(1);
#pragma unroll
    for (int m = 0; m < 4; ++m)
#pragma unroll
      for (int n = 0; n < 2; ++n) {
        acc[0][0][m][n] = __builtin_amdgcn_mfma_f32_16x16x32_bf16(af[m][0], b0f[n][0], acc[0][0][m][n], 0, 0, 0);
        acc[0][0][m][n] = __builtin_amdgcn_mfma_f32_16x16x32_bf16(af[m][1], b0f[n][1], acc[0][0][m][n], 0, 0, 0);
      }
    __builtin_amdgcn_s_setprio(0);
    asm volatile("s_waitcnt vmcnt(10)" ::: "memory");
    asm volatile("s_barrier" ::: "memory");

    // ---- ph2: quadrant (A0,B1); read B1 (4); reuse af; stage A.h0(t+2)
#pragma unroll
    for (int n = 0; n < 2; ++n) {
      const int row = 128 + wc2 * 32 + n * 16 + lane16;  // B rows 128..255 (h1)
#pragma unroll
      for (int kk = 0; kk < 2; ++kk)
        b1f[n][kk] = *(const bf16x8*)(bB + row * 64 + (((kk * 4 + quad) ^ (row & 7)) << 3));
    }
    stage_half512(A, m0, k2, K, aB, wave, lane);
    asm volatile("s_barrier" ::: "memory");
    asm volatile("s_waitcnt lgkmcnt(0)" ::: "memory");
    __builtin_amdgcn_sched_barrier(0);
    __builtin_amdgcn_s_setprio(1);
#pragma unroll
    for (int m = 0; m < 4; ++m)
#pragma unroll
      for (int n = 0; n < 2; ++n) {
        acc[0][1][m][n] = __builtin_amdgcn_mfma_f32_16x16x32_bf16(af[m][0], b1f[n][0], acc[0][1][m][n], 0, 0, 0);
        acc[0][1][m][n] = __builtin_amdgcn_mfma_f32_16x16x32_bf16(af[m][1], b1f[n][1], acc[0][1][m][n], 0, 0, 0);
      }
    __builtin_amdgcn_s_setprio(0);
    asm volatile("s_waitcnt vmcnt(10)" ::: "memory");
    asm volatile("s_barrier" ::: "memory");

    // ---- ph3: quadrant (A1,B1); read A1 (8); reuse b1f; stage B.h0(t+2)
#pragma unroll
    for (int m = 0; m < 4; ++m) {
      const int row = 128 + wr2 * 64 + m * 16 + lane16;  // A rows 128..255 (h1)
#pragma unroll
      for (int kk = 0; kk < 2; ++kk)
        af[m][kk] = *(const bf16x8*)(aB + row * 64 + (((kk * 4 + quad) ^ (row & 7)) << 3));
    }
    stage_half512(Bt, n0, k2, K, bB, wave, lane);
    asm volatile("s_barrier" ::: "memory");
    asm volatile("s_waitcnt lgkmcnt(0)" ::: "memory");
    __builtin_amdgcn_sched_barrier(0);
    __builtin_amdgcn_s_setprio(1);
#pragma unroll
    for (int m = 0; m < 4; ++m)
#pragma unroll
      for (int n = 0; n < 2; ++n) {
        acc[1][1][m][n] = __builtin_amdgcn_mfma_f32_16x16x32_bf16(af[m][0], b1f[n][0], acc[1][1][m][n], 0, 0, 0);
        acc[1][1][m][n] = __builtin_amdgcn_mfma_f32_16x16x32_bf16(af[m][1], b1f[n][1], acc[1][1][m][n], 0, 0, 0);
      }
    __builtin_amdgcn_s_setprio(0);
    asm volatile("s_waitcnt vmcnt(10)" ::: "memory");
    asm volatile("s_barrier" ::: "memory");

    // ---- ph4: quadrant (A1,B0); reuse af + b0f (no LDS reads); stage B.h1(t+2)
    stage_half512(Bt, n0 + 128, k2, K, bB + 8192, wave, lane);
    asm volatile("s_barrier" ::: "memory");
    __builtin_amdgcn_s_setprio(1);
#pragma unroll
    for (int m = 0; m < 4; ++m)
#pragma unroll
      for (int n = 0; n < 2; ++n) {
        acc[1][0][m][n] = __builtin_amdgcn_mfma_f32_16x16x32_bf16(af[m][0], b0f[n][0], acc[1][0][m][n], 0, 0, 0);
        acc[1][0][m][n] = __builtin_amdgcn_mfma_f32_16x16x32_bf16(af[m][1], b0f[n][1], acc[1][0][m][n], 0, 0, 0);
      }
    __builtin_amdgcn_s_setprio(0);
    asm volatile("s_waitcnt vmcnt(10)" ::: "memory");
    asm volatile("s_barrier" ::: "memory");
  }

  // drain stray clamped prefetches before LDS dealloc / kernel end
  asm volatile("s_waitcnt vmcnt(0)" ::: "memory");

  if (MODE == 2) {
    u16* op = (u16*)outp;
#pragma unroll
    for (int qa = 0; qa < 2; ++qa)
#pragma unroll
      for (int qb = 0; qb < 2; ++qb)
#pragma unroll
        for (int n = 0; n < 2; ++n) {
          const int col = (int)n0 + qb * 128 + wc2 * 32 + n * 16 + lane16;
          const float bv = bias[col];
#pragma unroll
          for (int m = 0; m < 4; ++m) {
            const long rbase = ((long)m0 + qa * 128 + wr2 * 64 + m * 16 + quad * 4) * N + col;
#pragma unroll
            for (int r = 0; r < 4; ++r)
              op[rbase + (long)r * N] = f2bf(fmaxf(acc[qa][qb][m][n][r] + bv, 0.0f));
          }
        }
  } else {
    u16* pp = (u16*)outp + (long)blockIdx.z * 4194304;  // per-z bf16 partial (4096x1024)
#pragma unroll
    for (int qa = 0; qa < 2; ++qa)
#pragma unroll
      for (int qb = 0; qb < 2; ++qb)
#pragma unroll
        for (int n = 0; n < 2; ++n) {
          const int col = (int)n0 + qb * 128 + wc2 * 32 + n * 16 + lane16;
#pragma unroll
          for (int m = 0; m < 4; ++m) {
            const long rbase = ((long)m0 + qa * 128 + wr2 * 64 + m * 16 + quad * 4) * N + col;
#pragma unroll
            for (int r = 0; r < 4; ++r)
              pp[rbase + (long)r * N] = f2bf(acc[qa][qb][m][n][r]);
          }
        }
  }
}

// -------- flash attention: 128-q blocks, 32 q/wave (best measured config: R5 layout) --------
// grid (16 q-tiles, 32 bh), XCD-remapped so all 16 q-tiles of one bh share an XCD L2.
// S^T = mfma(A=K,B=Q): lane holds 4 consecutive keys -> exp2 + v_perm pack -> ds_write_b64.
// P of waves 0/1 aliases ldsK (barrier between S-compute and pack); waves 2/3 dedicated.
// LDS ~50KB -> 3 blocks/CU. Mask folded post-MFMA only on !allv tiles (never for all-ones).
#define FA_C0 28.854239f  // 20 * log2(e) safety offset; scores |S|<~4 << 20
__global__ __launch_bounds__(256) void flash_attn(const u16* __restrict__ q,
                                                  const u16* __restrict__ k,
                                                  const u16* __restrict__ v,
                                                  const int* __restrict__ mask,
                                                  u16* __restrict__ ctx) {
  // XCD-aware remap: flat id -> (bh, qtile) s.t. same bh stays on one XCD (id&7).
  const int fid = blockIdx.y * 16 + blockIdx.x;
  const int xcd = fid & 7, slot = fid >> 3;
  const int bh = xcd * 4 + (slot >> 4);
  const int q0 = (slot & 15) * 128;
  const int b = bh >> 4, h = bh & 15;
  const int tid = threadIdx.x;
  const int wave = tid >> 6, lane = tid & 63;
  const int lane16 = lane & 15, quad = lane >> 4;

  const u16* qp = q + (long)bh * 2048 * 64;
  const u16* kp = k + (long)bh * 2048 * 64;
  const u16* vp = v + (long)bh * 64 * 2048;
  const int* mp = mask + b * 2048;

  __shared__ __align__(16) u16 ldsK[128 * 64];    // 16KB; P of waves 0/1 aliases
  __shared__ __align__(16) u16 ldsVT[64 * 128];   // 16KB
  __shared__ __align__(16) u16 ldsP23[2 * 4096];  // 16KB; P of waves 2/3
  __shared__ __align__(16) float ldsMask[128];
  __shared__ int ldsFlag[2];
  u16* myP = (wave < 2) ? (ldsK + wave * 4096) : (ldsP23 + (wave - 2) * 4096);

  bf16x8 qf[2][2];
#pragma unroll
  for (int g = 0; g < 2; ++g) {
    const long qrow = q0 + wave * 32 + g * 16 + lane16;
    qf[g][0] = *(const bf16x8*)(qp + qrow * 64 + quad * 8);
    qf[g][1] = *(const bf16x8*)(qp + qrow * 64 + 32 + quad * 8);
  }

  const f32x4 fzero = {0.f, 0.f, 0.f, 0.f};
  const f32x4 cC0 = {-FA_C0, -FA_C0, -FA_C0, -FA_C0};
  float l_loc[2] = {0.f, 0.f};
  f32x4 o_acc[2][4];
#pragma unroll
  for (int g = 0; g < 2; ++g)
#pragma unroll
    for (int j = 0; j < 4; ++j) o_acc[g][j] = fzero;

  const int xorm = (lane16 & 7) << 2;  // P chunk swizzle per q-row
  u16* const pw0 = myP + lane16 * 128;         // P write base, g=0
  u16* const pw1 = myP + (16 + lane16) * 128;  // g=1

  for (int kt = 0; kt < 2048; kt += 128) {
    stage128x64(kp, kt, 0, 64, ldsK, wave, lane);
    stage64x128(vp, kt, 2048, ldsVT, wave, lane);
    if (tid < 128) {
      int mv = mp[kt + tid];
      ldsMask[tid] = (mv == 0) ? -1.0e9f : 0.0f;
      unsigned long long bal = __ballot(mv != 0);
      if ((tid & 63) == 0) ldsFlag[tid >> 6] = (bal == ~0ull) ? 1 : 0;
    }
    __syncthreads();
    const bool allv = (ldsFlag[0] & ldsFlag[1]) != 0;

    // S^T = K @ Q^T  (128 keys x 32 q per wave); C-init = -C0
    f32x4 s_acc[8][2];
#pragma unroll
    for (int j = 0; j < 8; ++j) {
      int row = j * 16 + lane16;
      int c0i = quad ^ (row & 7);
      int c1i = (4 + quad) ^ (row & 7);
      bf16x8 kf0 = *(const bf16x8*)(ldsK + row * 64 + c0i * 8);
      bf16x8 kf1 = *(const bf16x8*)(ldsK + row * 64 + c1i * 8);
#pragma unroll
      for (int g = 0; g < 2; ++g) {
        f32x4 sa = __builtin_amdgcn_mfma_f32_16x16x32_bf16(kf0, qf[g][0], cC0, 0, 0, 0);
        sa = __builtin_amdgcn_mfma_f32_16x16x32_bf16(kf1, qf[g][1], sa, 0, 0, 0);
        s_acc[j][g] = sa;
      }
    }
    __syncthreads();  // all waves' K reads done; waves 0/1 may overwrite ldsK with P

    // p = 2^s (mask deferred: only on !allv tiles): pack 2x v_perm + 1 ds_write_b64
#pragma unroll
    for (int j = 0; j < 8; ++j) {
      int cw = ((4 * j + quad) ^ xorm) * 4;
#pragma unroll
      for (int g = 0; g < 2; ++g) {
        f32x4 sa = s_acc[j][g];
        if (!allv) {
          f32x4 mk = *(const f32x4*)(ldsMask + j * 16 + quad * 4);
          sa = sa + mk;
        }
        float p0 = __builtin_exp2f(sa[0]);
        float p1 = __builtin_exp2f(sa[1]);
        float p2 = __builtin_exp2f(sa[2]);
        float p3 = __builtin_exp2f(sa[3]);
        l_loc[g] += (p0 + p1) + (p2 + p3);
        uint2 pk;
        pk.x = __builtin_amdgcn_perm(fbits(p1), fbits(p0), 0x07060302u);  // bf16 trunc pair
        pk.y = __builtin_amdgcn_perm(fbits(p3), fbits(p2), 0x07060302u);
        *(uint2*)((g ? pw1 : pw0) + cw) = pk;
      }
    }
    // O += P @ V (myP wave-private; in-wave write->read ordering only)
#pragma unroll
    for (int kk = 0; kk < 4; ++kk) {
      int cr = ((8 * kk + 2 * quad) ^ xorm) * 4;
      bf16x8 pf0 = *(const bf16x8*)(pw0 + cr);
      bf16x8 pf1 = *(const bf16x8*)(pw1 + cr);
#pragma unroll
      for (int jj = 0; jj < 4; ++jj) {
        int row = jj * 16 + lane16;
        int cv = (kk * 4 + quad) ^ (row & 15);
        bf16x8 vf = *(const bf16x8*)(ldsVT + row * 128 + cv * 8);
        o_acc[0][jj] = __builtin_amdgcn_mfma_f32_16x16x32_bf16(pf0, vf, o_acc[0][jj], 0, 0, 0);
        o_acc[1][jj] = __builtin_amdgcn_mfma_f32_16x16x32_bf16(pf1, vf, o_acc[1][jj], 0, 0, 0);
      }
    }
    __syncthreads();  // P(aliased)/VT reads done before next stage overwrites
  }

  // l: sum across quads; broadcast per-o-row inverse
  float lr[2][4];
#pragma unroll
  for (int g = 0; g < 2; ++g) {
    float l = l_loc[g];
#pragma unroll
    for (int off = 16; off < 64; off <<= 1) l += __shfl_xor(l, off);
    float linv = 1.0f / l;  // valid for q = lane16 in every quad
#pragma unroll
    for (int r = 0; r < 4; ++r) lr[g][r] = __shfl(linv, quad * 4 + r);
  }

#pragma unroll
  for (int g = 0; g < 2; ++g)
#pragma unroll
    for (int jj = 0; jj < 4; ++jj)
#pragma unroll
      for (int r = 0; r < 4; ++r) {
        int sg = q0 + wave * 32 + g * 16 + quad * 4 + r;
        int d = jj * 16 + lane16;
        float val = o_acc[g][jj][r] * lr[g][r];
        ctx[((long)b * 2048 + sg) * 1024 + h * 64 + d] = f2bf(val);
      }
}

extern "C" void kernel_launch(void* const* d_in, const int* in_sizes, int n_in, void* d_out,
                              int out_size, void* d_ws, size_t ws_size, hipStream_t stream) {
  (void)in_sizes; (void)n_in; (void)out_size; (void)ws_size;
  const float* x  = (const float*)d_in[0];
  const int* mask = (const int*)d_in[1];
  const float* wq = (const float*)d_in[2];
  const float* wk = (const float*)d_in[3];
  const float* wv = (const float*)d_in[4];
  const float* wo = (const float*)d_in[5];
  const float* bq = (const float*)d_in[6];
  const float* bk = (const float*)d_in[7];
  const float* bv = (const float*)d_in[8];
  const float* bo = (const float*)d_in[9];
  const float* w1 = (const float*)d_in[10];
  const float* b1 = (const float*)d_in[11];
  const float* w2 = (const float*)d_in[12];
  const float* b2 = (const float*)d_in[13];
  const float* ln1_g = (const float*)d_in[14];
  const float* ln1_b = (const float*)d_in[15];
  const float* ln2_g = (const float*)d_in[16];
  const float* ln2_b = (const float*)d_in[17];
  float* out = (float*)d_out;

  u16* ws = (u16*)d_ws;
  u16* wqkvT = ws;                      // [0,3M) u16
  u16* woT = wqkvT + 3072 * 1024;       // [3M,4M)
  u16* w1T = woT + 1024 * 1024;         // [4M,8M)
  u16* w2T = w1T + 4096 * 1024;         // [8M,12M)
  u16* h   = w2T + 4096 * 1024;         // [12M,16M)  LN1 out; LN2 out
  u16* qb  = h + 4096 * 1024;           // [16M,20M)  Q; WO partial0
  u16* kb  = qb + 4096 * 1024;          // [20M,24M)  K; WO partial1
  u16* vb  = kb + 4096 * 1024;          // [24M,28M)  V^T
  u16* ctx = vb + 4096 * 1024;          // [28M,32M)
  u16* ffh = qb;                        // [16M,32M)  4096x4096 relu acts (qb..ctx dead)
  u16* f2p = ws;                        // [0,16M)    4 x FFN2 bf16 partials (weights dead)

  // one launch: wq/wk/wv/wo/w1/w2 transposes + LN1
  prep<<<16384, 256, 0, stream>>>(wq, wk, wv, wo, w1, w2, x, ln1_g, ln1_b,
                                  wqkvT, w1T, w2T, h);

  gemm_bt<0><<<dim3(24, 32), 256, 0, stream>>>(h, wqkvT, 4096, 3072, 1024, nullptr, bq, bk, bv,
                                               qb, kb, vb);

  flash_attn<<<dim3(16, 32), 256, 0, stream>>>(qb, kb, vb, mask, ctx);

  // WO: split-K x2, bf16 partials into qb (z0) / kb (z1), both dead after attention
  gemm_bt<1><<<dim3(8, 32, 2), 256, 0, stream>>>(ctx, woT, 4096, 1024, 1024, qb, nullptr,
                                                 nullptr, nullptr, kb, nullptr, nullptr);

  // fused: y = x + bo + P0 + P1 -> out (fp32 residual) and h = LN2(y) bf16
  ln_fuse<<<4096, 256, 0, stream>>>(x, bo, qb, kb, ln2_g, ln2_b, out, h);

  // FFN1: 256^2 quadrant 8-phase, grid 16x16 = 256 blocks (1/CU), relu+bias epilogue
  gemm8<2><<<dim3(16, 16), 512, 0, stream>>>(h, w1T, 4096, 4096, 1024, ffh, b1);

  // FFN2: split-K x4 (grid 4x16x4 = 256 blocks), bf16 partials into dead weight regions
  gemm8<1><<<dim3(4, 16, 4), 512, 0, stream>>>(ffh, w2T, 4096, 1024, 4096, f2p, nullptr);

  final_add<<<4096, 256, 0, stream>>>(out, b2, f2p, f2p + 4194304, f2p + 2 * 4194304,
                                      f2p + 3 * 4194304);
}

// Round 3
// 353.610 us; speedup vs baseline: 1.0843x; 1.0063x over previous
//
#include <hip/hip_runtime.h>

typedef unsigned short u16;
typedef unsigned int u32;
typedef __attribute__((ext_vector_type(8))) short bf16x8;
typedef __attribute__((ext_vector_type(4))) float f32x4;

__device__ __forceinline__ u16 f2bf(float f) {
  union { float f; unsigned int u; } x;
  x.f = f;
  unsigned int r = x.u + 0x7fffu + ((x.u >> 16) & 1u);
  return (u16)(r >> 16);
}

__device__ __forceinline__ float bf2f(u16 v) {
  union { unsigned int u; float f; } x;
  x.u = ((unsigned int)v) << 16;
  return x.f;
}

__device__ __forceinline__ u32 fbits(float f) {
  union { float f; u32 u; } x; x.f = f; return x.u;
}

__device__ __forceinline__ void async16(const u16* g, u16* l) {
  __builtin_amdgcn_global_load_lds((const __attribute__((address_space(1))) void*)g,
                                   (__attribute__((address_space(3))) void*)l, 16, 0, 0);
}

// Stage 128 rows x 64 cols bf16 tile (256 threads). LDS slot s: row=s>>3, stored chunk (s&7)
// holds global 16B chunk c = (s&7) ^ (row&7)  (XOR swizzle -> conflict-free b128 reads).
__device__ __forceinline__ void stage128x64(const u16* __restrict__ src, long row0, int k0,
                                            int ld, u16* lds, int wave, int lane) {
#pragma unroll
  for (int r = 0; r < 4; ++r) {
    int s = r * 256 + wave * 64 + lane;
    int row = s >> 3;
    int c = (s & 7) ^ (row & 7);
    async16(src + (row0 + row) * (long)ld + k0 + c * 8, lds + (r * 256 + wave * 64) * 8);
  }
}

// Same 128x64 half-tile staging, but for a 512-thread block (2 issues/thread).
__device__ __forceinline__ void stage_half512(const u16* __restrict__ src, long row0, int k0,
                                              int ld, u16* lbase, int wave, int lane) {
#pragma unroll
  for (int r = 0; r < 2; ++r) {
    int s = r * 512 + wave * 64 + lane;
    int row = s >> 3;
    int c = (s & 7) ^ (row & 7);
    async16(src + (row0 + row) * (long)ld + k0 + c * 8, lbase + (r * 512 + wave * 64) * 8);
  }
}

// Stage 64 rows x 128 cols (V^T tile): 16 chunks/row, swizzle c = (s&15)^(row&15).
__device__ __forceinline__ void stage64x128(const u16* __restrict__ src, int col0, int ld,
                                            u16* lds, int wave, int lane) {
#pragma unroll
  for (int r = 0; r < 4; ++r) {
    int s = r * 256 + wave * 64 + lane;
    int row = s >> 4;
    int c = (s & 15) ^ (row & 15);
    async16(src + (long)row * ld + col0 + c * 8, lds + (r * 256 + wave * 64) * 8);
  }
}

// ---------------- LayerNorm core (torch-style: unbiased std, /(std+eps)) ----------------
__device__ __forceinline__ void ln_core(float4 v, const float* g, const float* b, int t,
                                        u16* outrow) {
  float s = v.x + v.y + v.z + v.w;
  float ss = v.x * v.x + v.y * v.y + v.z * v.z + v.w * v.w;
#pragma unroll
  for (int off = 32; off; off >>= 1) {
    s += __shfl_xor(s, off);
    ss += __shfl_xor(ss, off);
  }
  __shared__ float red[8];
  int wave = t >> 6, lane = t & 63;
  if (lane == 0) { red[wave] = s; red[wave + 4] = ss; }
  __syncthreads();
  float tot = red[0] + red[1] + red[2] + red[3];
  float tots = red[4] + red[5] + red[6] + red[7];
  float mean = tot * (1.0f / 1024.0f);
  float var = (tots - 1024.0f * mean * mean) * (1.0f / 1023.0f);
  var = fmaxf(var, 0.0f);
  float inv = 1.0f / (sqrtf(var) + 1e-6f);
  float4 gv = ((const float4*)g)[t];
  float4 bv = ((const float4*)b)[t];
  union { unsigned long long u64; u16 h[4]; } o;
  o.h[0] = f2bf(gv.x * (v.x - mean) * inv + bv.x);
  o.h[1] = f2bf(gv.y * (v.y - mean) * inv + bv.y);
  o.h[2] = f2bf(gv.z * (v.z - mean) * inv + bv.z);
  o.h[3] = f2bf(gv.w * (v.w - mean) * inv + bv.w);
  *(unsigned long long*)(outrow + t * 4) = o.u64;
}

// ---------------- prep: all weight transposes + LN1 in ONE launch ----------------
// 16384 blocks: [0,4k) wq/wk/wv/wo transpose; [4k,8k) LN1; [8k,12k) w1; [12k,16k) w2.
__global__ __launch_bounds__(256) void prep(const float* __restrict__ wq,
                                            const float* __restrict__ wk,
                                            const float* __restrict__ wv,
                                            const float* __restrict__ wo,
                                            const float* __restrict__ w1,
                                            const float* __restrict__ w2,
                                            const float* __restrict__ x,
                                            const float* __restrict__ ln1_g,
                                            const float* __restrict__ ln1_b,
                                            u16* __restrict__ wqkvT,  // + woT contiguous
                                            u16* __restrict__ w1T,
                                            u16* __restrict__ w2T,
                                            u16* __restrict__ hout) {
  const int bid = blockIdx.x;
  const int part = bid >> 12;
  const int local = bid & 4095;
  const int t = threadIdx.x;
  if (part == 1) {
    float4 v = ((const float4*)(x + (long)local * 1024))[t];
    ln_core(v, ln1_g, ln1_b, t, hout + (long)local * 1024);
    return;
  }
  __shared__ float tile[32][33];
  const float* src; u16* dst; int C, R, bx, by;
  if (part == 0) {
    int sub = local >> 10;
    src = sub == 0 ? wq : (sub == 1 ? wk : (sub == 2 ? wv : wo));
    dst = wqkvT + (long)sub * 1024 * 1024;
    C = 1024; R = 1024; bx = local & 31; by = (local >> 5) & 31;
  } else if (part == 2) {
    src = w1; dst = w1T; C = 4096; R = 1024; bx = local & 127; by = local >> 7;
  } else {
    src = w2; dst = w2T; C = 1024; R = 4096; bx = local & 31; by = local >> 5;
  }
  int c0 = bx * 32, r0 = by * 32;
  int tx = t & 31, ty = t >> 5;
#pragma unroll
  for (int i = 0; i < 32; i += 8)
    tile[ty + i][tx] = src[(long)(r0 + ty + i) * C + c0 + tx];
  __syncthreads();
#pragma unroll
  for (int i = 0; i < 32; i += 8)
    dst[(long)(c0 + ty + i) * R + r0 + tx] = f2bf(tile[tx][ty + i]);
}

// y = x + bres + P0..P3 (WO split-K4 reduce); write y fp32 and LN2(y) bf16.
// NOTE: p0 may alias hout (per-thread read-before-write on identical addresses) -> NO restrict.
__global__ __launch_bounds__(256) void ln_fuse(const float* x, const float* bres,
                                               const u16* p0, const u16* p1,
                                               const u16* p2, const u16* p3,
                                               const float* g, const float* b,
                                               float* yout, u16* hout) {
  int row = blockIdx.x, t = threadIdx.x;
  long base = (long)row * 1024;
  float4 xv = ((const float4*)(x + base))[t];
  float4 bo = ((const float4*)bres)[t];
  ushort4 a = ((const ushort4*)(p0 + base))[t];
  ushort4 c = ((const ushort4*)(p1 + base))[t];
  ushort4 d = ((const ushort4*)(p2 + base))[t];
  ushort4 e = ((const ushort4*)(p3 + base))[t];
  float4 y;
  y.x = xv.x + bo.x + (bf2f(a.x) + bf2f(c.x)) + (bf2f(d.x) + bf2f(e.x));
  y.y = xv.y + bo.y + (bf2f(a.y) + bf2f(c.y)) + (bf2f(d.y) + bf2f(e.y));
  y.z = xv.z + bo.z + (bf2f(a.z) + bf2f(c.z)) + (bf2f(d.z) + bf2f(e.z));
  y.w = xv.w + bo.w + (bf2f(a.w) + bf2f(c.w)) + (bf2f(d.w) + bf2f(e.w));
  ((float4*)(yout + base))[t] = y;
  ln_core(y, g, b, t, hout + base);
}

// out += b2 + P0 + P1 + P2 (FFN2 split-K reduce: 3 bf16 partials; z3 already atomically
// accumulated fp32 into out by gemm8<3>).
__global__ __launch_bounds__(256) void final_add(float* __restrict__ out,
                                                 const float* __restrict__ b2,
                                                 const u16* __restrict__ p0,
                                                 const u16* __restrict__ p1,
                                                 const u16* __restrict__ p2) {
  int row = blockIdx.x, t = threadIdx.x;
  long base = (long)row * 1024;
  float4 o = ((float4*)(out + base))[t];
  float4 bb = ((const float4*)b2)[t];
  ushort4 a = ((const ushort4*)(p0 + base))[t];
  ushort4 c = ((const ushort4*)(p1 + base))[t];
  ushort4 d = ((const ushort4*)(p2 + base))[t];
  o.x += bb.x + (bf2f(a.x) + bf2f(c.x)) + bf2f(d.x);
  o.y += bb.y + (bf2f(a.y) + bf2f(c.y)) + bf2f(d.y);
  o.z += bb.z + (bf2f(a.z) + bf2f(c.z)) + bf2f(d.z);
  o.w += bb.w + (bf2f(a.w) + bf2f(c.w)) + bf2f(d.w);
  ((float4*)(out + base))[t] = o;
}

// ============ 256^2 8-phase GEMM, quadrant-rotating schedule (deep prefetch) ============
// C = A(MxK) @ Bt(NxK)^T. BM=BN=256, BK=64, 512 threads = 8 waves. LDS 128 KiB dbuf.
// Each wave computes a slice of ALL FOUR (A-half x B-half) quadrants, one per phase:
//   ph1:(A0,B0) fresh A0+B0   ph2:(A0,B1) fresh B1, reuse A0 regs
//   ph3:(A1,B1) fresh A1      ph4:(A1,B0) reuse A1 + B0 regs (B0 lives ph1->ph4)
// => every LDS region is ds_read in exactly ONE phase, so each half-tile stage is issued
// 6-7 phases before consumption. Per-phase stage (region died previous phase):
//   ph1(t): A.h1(t+1)   ph2(t): A.h0(t+2)   ph3(t): B.h0(t+2)   ph4(t): B.h1(t+2)
// Uniform s_waitcnt vmcnt(10) (cap 5 stages in flight) before EVERY trailing barrier:
// retires exactly one stage/phase in steady state; youngest-required is always >=4.5
// phases (~1000 cyc) old => no HBM-latency stall. Raw s_barrier only (never __syncthreads:
// it drains vmcnt(0)). Requires nT>=2.
// SWZ=1: XCD-bijective 2D chunk (4 y-quads x 2 x-halves; requires gridDim.y==16, even
// gridDim.x, z==1) so each XCD's private L2 keeps its A/B panels instead of replicating.
// MODE 0: QKV epilogue (+bias; q*=0.125*log2e; Q/K scatter to (bh,s,d); V via LDS
//         transpose to (bh,d,s) 64B-contiguous stores). sel by n0: 0=Q,1=K,2=V.
// MODE 1: bf16 partial per z-slice; ptr z0..z3 = outp,q_out,k_out,v_out (all dead regions).
// MODE 2: out bf16 = relu(acc + bias[col]).
// MODE 3: like MODE 1 for z<3; z==3 accumulates fp32 via unsafeAtomicAdd into (float*)v_out
//         (only 3 dead 8MB regions exist at FFN2 time; R2's 4th partial raced with live w2T).
template <int MODE, int SWZ>
__global__ __launch_bounds__(512, 1) void gemm8(const u16* __restrict__ A,
                                                const u16* __restrict__ Bt, int M, int N, int K,
                                                void* __restrict__ outp,
                                                const float* __restrict__ bias,
                                                const float* __restrict__ bias1,
                                                const float* __restrict__ bias2,
                                                u16* __restrict__ q_out, u16* __restrict__ k_out,
                                                u16* __restrict__ v_out) {
  __shared__ __align__(16) u16 lds[65536];  // 128 KiB
  (void)M;
  const int tid = threadIdx.x;
  const int wave = tid >> 6, lane = tid & 63;
  const int lane16 = lane & 15, quad = lane >> 4;
  const int wr2 = wave >> 2, wc2 = wave & 3;  // 2 x 4 wave grid within a quadrant
  int bx = blockIdx.x, by = blockIdx.y;
  if (SWZ) {
    const int fid = by * gridDim.x + bx;
    const int xcd = fid & 7, slot = fid >> 3;
    const int nxh = gridDim.x >> 1;
    bx = (xcd & 1) * nxh + slot % nxh;
    by = (xcd >> 1) * 4 + slot / nxh;
  }
  const long m0 = (long)by * 256;
  const long n0 = (long)bx * 256;
  const int kLen = K / gridDim.z;
  const int kBeg = blockIdx.z * kLen;
  const int nT = kLen >> 6;

  u16* const ldsA = lds;
  u16* const ldsB = lds + 32768;

  const f32x4 fzero = {0.f, 0.f, 0.f, 0.f};
  f32x4 acc[2][2][4][2];  // [qa][qb][m][n]
#pragma unroll
  for (int qa = 0; qa < 2; ++qa)
#pragma unroll
    for (int qb = 0; qb < 2; ++qb)
#pragma unroll
      for (int m = 0; m < 4; ++m)
#pragma unroll
        for (int n = 0; n < 2; ++n) acc[qa][qb][m][n] = fzero;

  // prologue: steady-state issue order [Ah0(0),Bh0(0),Bh1(0),Ah1(0),Ah0(1),Bh0(1),Bh1(1)]
  stage_half512(A,  m0,       kBeg,      K, ldsA,                 wave, lane);
  stage_half512(Bt, n0,       kBeg,      K, ldsB,                 wave, lane);
  stage_half512(Bt, n0 + 128, kBeg,      K, ldsB + 8192,          wave, lane);
  stage_half512(A,  m0 + 128, kBeg,      K, ldsA + 8192,          wave, lane);
  stage_half512(A,  m0,       kBeg + 64, K, ldsA + 16384,         wave, lane);
  stage_half512(Bt, n0,       kBeg + 64, K, ldsB + 16384,         wave, lane);
  stage_half512(Bt, n0 + 128, kBeg + 64, K, ldsB + 16384 + 8192,  wave, lane);
  asm volatile("s_waitcnt vmcnt(10)" ::: "memory");  // retire Ah0(0),Bh0(0)
  asm volatile("s_barrier" ::: "memory");

  for (int t = 0; t < nT; ++t) {
    u16* const aB = ldsA + (t & 1) * 16384;
    u16* const bB = ldsB + (t & 1) * 16384;
    u16* const aN1 = ldsA + ((t + 1) & 1) * 16384;
    const int k1 = kBeg + (t + 1 < nT ? t + 1 : nT - 1) * 64;  // clamped strays land in
    const int k2 = kBeg + (t + 2 < nT ? t + 2 : nT - 1) * 64;  // already-dead regions

    bf16x8 af[4][2], b0f[2][2], b1f[2][2];

    // ---- ph1: quadrant (A0,B0); read A0 (8) + B0 (4); stage A.h1(t+1)
#pragma unroll
    for (int m = 0; m < 4; ++m) {
      const int row = wr2 * 64 + m * 16 + lane16;  // A rows 0..127 (h0)
#pragma unroll
      for (int kk = 0; kk < 2; ++kk)
        af[m][kk] = *(const bf16x8*)(aB + row * 64 + (((kk * 4 + quad) ^ (row & 7)) << 3));
    }
#pragma unroll
    for (int n = 0; n < 2; ++n) {
      const int row = wc2 * 32 + n * 16 + lane16;  // B rows 0..127 (h0)
#pragma unroll
      for (int kk = 0; kk < 2; ++kk)
        b0f[n][kk] = *(const bf16x8*)(bB + row * 64 + (((kk * 4 + quad) ^ (row & 7)) << 3));
    }
    stage_half512(A, m0 + 128, k1, K, aN1 + 8192, wave, lane);
    asm volatile("s_barrier" ::: "memory");
    asm volatile("s_waitcnt lgkmcnt(0)" ::: "memory");
    __builtin_amdgcn_sched_barrier(0);
    __builtin_amdgcn_s_setprio(1);
#pragma unroll
    for (int m = 0; m < 4; ++m)
#pragma unroll
      for (int n = 0; n < 2; ++n) {
        acc[0][0][m][n] = __builtin_amdgcn_mfma_f32_16x16x32_bf16(af[m][0], b0f[n][0], acc[0][0][m][n], 0, 0, 0);
        acc[0][0][m][n] = __builtin_amdgcn_mfma_f32_16x16x32_bf16(af[m][1], b0f[n][1], acc[0][0][m][n], 0, 0, 0);
      }
    __builtin_amdgcn_s_setprio(0);
    asm volatile("s_waitcnt vmcnt(10)" ::: "memory");
    asm volatile("s_barrier" ::: "memory");

    // ---- ph2: quadrant (A0,B1); read B1 (4); reuse af; stage A.h0(t+2)
#pragma unroll
    for (int n = 0; n < 2; ++n) {
      const int row = 128 + wc2 * 32 + n * 16 + lane16;  // B rows 128..255 (h1)
#pragma unroll
      for (int kk = 0; kk < 2; ++kk)
        b1f[n][kk] = *(const bf16x8*)(bB + row * 64 + (((kk * 4 + quad) ^ (row & 7)) << 3));
    }
    stage_half512(A, m0, k2, K, aB, wave, lane);
    asm volatile("s_barrier" ::: "memory");
    asm volatile("s_waitcnt lgkmcnt(0)" ::: "memory");
    __builtin_amdgcn_sched_barrier(0);
    __builtin_amdgcn_s_setprio(1);
#pragma unroll
    for (int m = 0; m < 4; ++m)
#pragma unroll
      for (int n = 0; n < 2; ++n) {
        acc[0][1][m][n] = __builtin_amdgcn_mfma_f32_16x16x32_bf16(af[m][0], b1f[n][0], acc[0][1][m][n], 0, 0, 0);
        acc[0][1][m][n] = __builtin_amdgcn_mfma_f32_16x16x32_bf16(af[m][1], b1f[n][1], acc[0][1][m][n], 0, 0, 0);
      }
    __builtin_amdgcn_s_setprio(0);
    asm volatile("s_waitcnt vmcnt(10)" ::: "memory");
    asm volatile("s_barrier" ::: "memory");

    // ---- ph3: quadrant (A1,B1); read A1 (8); reuse b1f; stage B.h0(t+2)
#pragma unroll
    for (int m = 0; m < 4; ++m) {
      const int row = 128 + wr2 * 64 + m * 16 + lane16;  // A rows 128..255 (h1)
#pragma unroll
      for (int kk = 0; kk < 2; ++kk)
        af[m][kk] = *(const bf16x8*)(aB + row * 64 + (((kk * 4 + quad) ^ (row & 7)) << 3));
    }
    stage_half512(Bt, n0, k2, K, bB, wave, lane);
    asm volatile("s_barrier" ::: "memory");
    asm volatile("s_waitcnt lgkmcnt(0)" ::: "memory");
    __builtin_amdgcn_sched_barrier(0);
    __builtin_amdgcn_s_setprio(1);
#pragma unroll
    for (int m = 0; m < 4; ++m)
#pragma unroll
      for (int n = 0; n < 2; ++n) {
        acc[1][1][m][n] = __builtin_amdgcn_mfma_f32_16x16x32_bf16(af[m][0], b1f[n][0], acc[1][1][m][n], 0, 0, 0);
        acc[1][1][m][n] = __builtin_amdgcn_mfma_f32_16x16x32_bf16(af[m][1], b1f[n][1], acc[1][1][m][n], 0, 0, 0);
      }
    __builtin_amdgcn_s_setprio(0);
    asm volatile("s_waitcnt vmcnt(10)" ::: "memory");
    asm volatile("s_barrier" ::: "memory");

    // ---- ph4: quadrant (A1,B0); reuse af + b0f (no LDS reads); stage B.h1(t+2)
    stage_half512(Bt, n0 + 128, k2, K, bB + 8192, wave, lane);
    asm volatile("s_barrier" ::: "memory");
    __builtin_amdgcn_s_setprio(1);
#pragma unroll
    for (int m = 0; m < 4; ++m)
#pragma unroll
      for (int n = 0; n < 2; ++n) {
        acc[1][0][m][n] = __builtin_amdgcn_mfma_f32_16x16x32_bf16(af[m][0], b0f[n][0], acc[1][0][m][n], 0, 0, 0);
        acc[1][0][m][n] = __builtin_amdgcn_mfma_f32_16x16x32_bf16(af[m][1], b0f[n][1], acc[1][0][m][n], 0, 0, 0);
      }
    __builtin_amdgcn_s_setprio(0);
    asm volatile("s_waitcnt vmcnt(10)" ::: "memory");
    asm volatile("s_barrier" ::: "memory");
  }

  // drain stray clamped prefetches (they WRITE lds) before epilogue / LDS reuse
  asm volatile("s_waitcnt vmcnt(0)" ::: "memory");

  if (MODE == 0) {
    const int sel = (int)(n0 >> 10);  // 0=Q, 1=K, 2=V (256-col blocks never span kinds)
    if (sel == 2) {
      // V: bias + transpose via LDS (128x136 pad), 64B-contiguous stores to (bh,d,s).
#pragma unroll
      for (int qa = 0; qa < 2; ++qa)
#pragma unroll
        for (int qb = 0; qb < 2; ++qb) {
          __syncthreads();  // also orders vs stray global_load_lds writes (all drained)
#pragma unroll
          for (int n = 0; n < 2; ++n) {
            const int lcol = wc2 * 32 + n * 16 + lane16;
            const float bvj = bias2[(int)(n0 - 2048) + qb * 128 + lcol];
#pragma unroll
            for (int m = 0; m < 4; ++m)
#pragma unroll
              for (int r = 0; r < 4; ++r) {
                const int lrow = wr2 * 64 + m * 16 + quad * 4 + r;
                lds[lcol * 136 + lrow] = f2bf(acc[qa][qb][m][n][r] + bvj);
              }
          }
          __syncthreads();
          const int lcol = tid >> 2, seg = tid & 3;
          const int cc = (int)(n0 - 2048) + qb * 128 + lcol;
          const int head = cc >> 6, d = cc & 63;
          const int bI = (int)((m0 + qa * 128) >> 11);
          const int s0 = (int)((m0 + qa * 128) & 2047);
          u16* dst = v_out + ((long)(bI * 16 + head) * 64 + d) * 2048 + s0 + seg * 32;
          const u16* s = lds + lcol * 136 + seg * 32;
#pragma unroll
          for (int c2 = 0; c2 < 4; ++c2) ((uint4*)dst)[c2] = ((const uint4*)s)[c2];
        }
      return;
    }
    // Q/K: +bias (Q also * 1/8*log2e), scatter to (bh, s, d)
    u16* qk = sel == 0 ? q_out : k_out;
    const float* bb = sel == 0 ? bias : bias1;
#pragma unroll
    for (int qa = 0; qa < 2; ++qa)
#pragma unroll
      for (int qb = 0; qb < 2; ++qb)
#pragma unroll
        for (int n = 0; n < 2; ++n) {
          const int col = (int)n0 + qb * 128 + wc2 * 32 + n * 16 + lane16;
          const int cc = col & 1023;
          const float bv = bb[cc];
          const int head = cc >> 6, d = cc & 63;
#pragma unroll
          for (int m = 0; m < 4; ++m) {
            const int rw = (int)m0 + qa * 128 + wr2 * 64 + m * 16 + quad * 4;
#pragma unroll
            for (int r = 0; r < 4; ++r) {
              const int row = rw + r;
              const int bI = row >> 11, sS = row & 2047;
              const long bh = (long)bI * 16 + head;
              float vv = acc[qa][qb][m][n][r] + bv;
              if (sel == 0) vv *= 0.18033688f;  // 1/8 * log2(e)
              qk[(bh * 2048 + sS) * 64 + d] = f2bf(vv);
            }
          }
        }
  } else if (MODE == 2) {
    u16* op = (u16*)outp;
#pragma unroll
    for (int qa = 0; qa < 2; ++qa)
#pragma unroll
      for (int qb = 0; qb < 2; ++qb)
#pragma unroll
        for (int n = 0; n < 2; ++n) {
          const int col = (int)n0 + qb * 128 + wc2 * 32 + n * 16 + lane16;
          const float bv = bias[col];
#pragma unroll
          for (int m = 0; m < 4; ++m) {
            const long rbase = ((long)m0 + qa * 128 + wr2 * 64 + m * 16 + quad * 4) * N + col;
#pragma unroll
            for (int r = 0; r < 4; ++r)
              op[rbase + (long)r * N] = f2bf(fmaxf(acc[qa][qb][m][n][r] + bv, 0.0f));
          }
        }
  } else {  // MODE 1 / MODE 3
    const int z = blockIdx.z;
    if (MODE == 3 && z == 3) {
      float* op = (float*)v_out;  // fp32 accumulate into residual (no bias; final_add adds b2)
#pragma unroll
      for (int qa = 0; qa < 2; ++qa)
#pragma unroll
        for (int qb = 0; qb < 2; ++qb)
#pragma unroll
          for (int n = 0; n < 2; ++n) {
            const int col = (int)n0 + qb * 128 + wc2 * 32 + n * 16 + lane16;
#pragma unroll
            for (int m = 0; m < 4; ++m) {
              const long rbase = ((long)m0 + qa * 128 + wr2 * 64 + m * 16 + quad * 4) * N + col;
#pragma unroll
              for (int r = 0; r < 4; ++r)
                unsafeAtomicAdd(op + rbase + (long)r * N, acc[qa][qb][m][n][r]);
            }
          }
    } else {
      u16* pp = z == 0 ? (u16*)outp : (z == 1 ? q_out : (z == 2 ? k_out : v_out));
#pragma unroll
      for (int qa = 0; qa < 2; ++qa)
#pragma unroll
        for (int qb = 0; qb < 2; ++qb)
#pragma unroll
          for (int n = 0; n < 2; ++n) {
            const int col = (int)n0 + qb * 128 + wc2 * 32 + n * 16 + lane16;
#pragma unroll
            for (int m = 0; m < 4; ++m) {
              const long rbase = ((long)m0 + qa * 128 + wr2 * 64 + m * 16 + quad * 4) * N + col;
#pragma unroll
              for (int r = 0; r < 4; ++r)
                pp[rbase + (long)r * N] = f2bf(acc[qa][qb][m][n][r]);
            }
          }
    }
  }
}

// -------- flash attention: 128-q blocks, 32 q/wave (best measured config: R5 layout) --------
// grid (16 q-tiles, 32 bh), XCD-remapped so all 16 q-tiles of one bh share an XCD L2.
// S^T = mfma(A=K,B=Q): lane holds 4 consecutive keys -> exp2 + v_perm pack -> ds_write_b64.
// P of waves 0/1 aliases ldsK (barrier between S-compute and pack); waves 2/3 dedicated.
// LDS ~50KB -> 3 blocks/CU. Mask folded post-MFMA only on !allv tiles (never for all-ones).
#define FA_C0 28.854239f  // 20 * log2(e) safety offset; scores |S|<~4 << 20
__global__ __launch_bounds__(256) void flash_attn(const u16* __restrict__ q,
                                                  const u16* __restrict__ k,
                                                  const u16* __restrict__ v,
                                                  const int* __restrict__ mask,
                                                  u16* __restrict__ ctx) {
  // XCD-aware remap: flat id -> (bh, qtile) s.t. same bh stays on one XCD (id&7).
  const int fid = blockIdx.y * 16 + blockIdx.x;
  const int xcd = fid & 7, slot = fid >> 3;
  const int bh = xcd * 4 + (slot >> 4);
  const int q0 = (slot & 15) * 128;
  const int b = bh >> 4, h = bh & 15;
  const int tid = threadIdx.x;
  const int wave = tid >> 6, lane = tid & 63;
  const int lane16 = lane & 15, quad = lane >> 4;

  const u16* qp = q + (long)bh * 2048 * 64;
  const u16* kp = k + (long)bh * 2048 * 64;
  const u16* vp = v + (long)bh * 64 * 2048;
  const int* mp = mask + b * 2048;

  __shared__ __align__(16) u16 ldsK[128 * 64];    // 16KB; P of waves 0/1 aliases
  __shared__ __align__(16) u16 ldsVT[64 * 128];   // 16KB
  __shared__ __align__(16) u16 ldsP23[2 * 4096];  // 16KB; P of waves 2/3
  __shared__ __align__(16) float ldsMask[128];
  __shared__ int ldsFlag[2];
  u16* myP = (wave < 2) ? (ldsK + wave * 4096) : (ldsP23 + (wave - 2) * 4096);

  bf16x8 qf[2][2];
#pragma unroll
  for (int g = 0; g < 2; ++g) {
    const long qrow = q0 + wave * 32 + g * 16 + lane16;
    qf[g][0] = *(const bf16x8*)(qp + qrow * 64 + quad * 8);
    qf[g][1] = *(const bf16x8*)(qp + qrow * 64 + 32 + quad * 8);
  }

  const f32x4 fzero = {0.f, 0.f, 0.f, 0.f};
  const f32x4 cC0 = {-FA_C0, -FA_C0, -FA_C0, -FA_C0};
  float l_loc[2] = {0.f, 0.f};
  f32x4 o_acc[2][4];
#pragma unroll
  for (int g = 0; g < 2; ++g)
#pragma unroll
    for (int j = 0; j < 4; ++j) o_acc[g][j] = fzero;

  const int xorm = (lane16 & 7) << 2;  // P chunk swizzle per q-row
  u16* const pw0 = myP + lane16 * 128;         // P write base, g=0
  u16* const pw1 = myP + (16 + lane16) * 128;  // g=1

  for (int kt = 0; kt < 2048; kt += 128) {
    stage128x64(kp, kt, 0, 64, ldsK, wave, lane);
    stage64x128(vp, kt, 2048, ldsVT, wave, lane);
    if (tid < 128) {
      int mv = mp[kt + tid];
      ldsMask[tid] = (mv == 0) ? -1.0e9f : 0.0f;
      unsigned long long bal = __ballot(mv != 0);
      if ((tid & 63) == 0) ldsFlag[tid >> 6] = (bal == ~0ull) ? 1 : 0;
    }
    __syncthreads();
    const bool allv = (ldsFlag[0] & ldsFlag[1]) != 0;

    // S^T = K @ Q^T  (128 keys x 32 q per wave); C-init = -C0
    f32x4 s_acc[8][2];
    __builtin_amdgcn_s_setprio(1);
#pragma unroll
    for (int j = 0; j < 8; ++j) {
      int row = j * 16 + lane16;
      int c0i = quad ^ (row & 7);
      int c1i = (4 + quad) ^ (row & 7);
      bf16x8 kf0 = *(const bf16x8*)(ldsK + row * 64 + c0i * 8);
      bf16x8 kf1 = *(const bf16x8*)(ldsK + row * 64 + c1i * 8);
#pragma unroll
      for (int g = 0; g < 2; ++g) {
        f32x4 sa = __builtin_amdgcn_mfma_f32_16x16x32_bf16(kf0, qf[g][0], cC0, 0, 0, 0);
        sa = __builtin_amdgcn_mfma_f32_16x16x32_bf16(kf1, qf[g][1], sa, 0, 0, 0);
        s_acc[j][g] = sa;
      }
    }
    __builtin_amdgcn_s_setprio(0);
    __syncthreads();  // all waves' K reads done; waves 0/1 may overwrite ldsK with P

    // p = 2^s (mask deferred: only on !allv tiles): pack 2x v_perm + 1 ds_write_b64
#pragma unroll
    for (int j = 0; j < 8; ++j) {
      int cw = ((4 * j + quad) ^ xorm) * 4;
#pragma unroll
      for (int g = 0; g < 2; ++g) {
        f32x4 sa = s_acc[j][g];
        if (!allv) {
          f32x4 mk = *(const f32x4*)(ldsMask + j * 16 + quad * 4);
          sa = sa + mk;
        }
        float p0 = __builtin_exp2f(sa[0]);
        float p1 = __builtin_exp2f(sa[1]);
        float p2 = __builtin_exp2f(sa[2]);
        float p3 = __builtin_exp2f(sa[3]);
        l_loc[g] += (p0 + p1) + (p2 + p3);
        uint2 pk;
        pk.x = __builtin_amdgcn_perm(fbits(p1), fbits(p0), 0x07060302u);  // bf16 trunc pair
        pk.y = __builtin_amdgcn_perm(fbits(p3), fbits(p2), 0x07060302u);
        *(uint2*)((g ? pw1 : pw0) + cw) = pk;
      }
    }
    // O += P @ V (myP wave-private; in-wave write->read ordering only)
    __builtin_amdgcn_s_setprio(1);
#pragma unroll
    for (int kk = 0; kk < 4; ++kk) {
      int cr = ((8 * kk + 2 * quad) ^ xorm) * 4;
      bf16x8 pf0 = *(const bf16x8*)(pw0 + cr);
      bf16x8 pf1 = *(const bf16x8*)(pw1 + cr);
#pragma unroll
      for (int jj = 0; jj < 4; ++jj) {
        int row = jj * 16 + lane16;
        int cv = (kk * 4 + quad) ^ (row & 15);
        bf16x8 vf = *(const bf16x8*)(ldsVT + row * 128 + cv * 8);
        o_acc[0][jj] = __builtin_amdgcn_mfma_f32_16x16x32_bf16(pf0, vf, o_acc[0][jj], 0, 0, 0);
        o_acc[1][jj] = __builtin_amdgcn_mfma_f32_16x16x32_bf16(pf1, vf, o_acc[1][jj], 0, 0, 0);
      }
    }
    __builtin_amdgcn_s_setprio(0);
    __syncthreads();  // P(aliased)/VT reads done before next stage overwrites
  }

  // l: sum across quads; broadcast per-o-row inverse
  float lr[2][4];
#pragma unroll
  for (int g = 0; g < 2; ++g) {
    float l = l_loc[g];
#pragma unroll
    for (int off = 16; off < 64; off <<= 1) l += __shfl_xor(l, off);
    float linv = 1.0f / l;  // valid for q = lane16 in every quad
#pragma unroll
    for (int r = 0; r < 4; ++r) lr[g][r] = __shfl(linv, quad * 4 + r);
  }

#pragma unroll
  for (int g = 0; g < 2; ++g)
#pragma unroll
    for (int jj = 0; jj < 4; ++jj)
#pragma unroll
      for (int r = 0; r < 4; ++r) {
        int sg = q0 + wave * 32 + g * 16 + quad * 4 + r;
        int d = jj * 16 + lane16;
        float val = o_acc[g][jj][r] * lr[g][r];
        ctx[((long)b * 2048 + sg) * 1024 + h * 64 + d] = f2bf(val);
      }
}

extern "C" void kernel_launch(void* const* d_in, const int* in_sizes, int n_in, void* d_out,
                              int out_size, void* d_ws, size_t ws_size, hipStream_t stream) {
  (void)in_sizes; (void)n_in; (void)out_size; (void)ws_size;
  const float* x  = (const float*)d_in[0];
  const int* mask = (const int*)d_in[1];
  const float* wq = (const float*)d_in[2];
  const float* wk = (const float*)d_in[3];
  const float* wv = (const float*)d_in[4];
  const float* wo = (const float*)d_in[5];
  const float* bq = (const float*)d_in[6];
  const float* bk = (const float*)d_in[7];
  const float* bv = (const float*)d_in[8];
  const float* bo = (const float*)d_in[9];
  const float* w1 = (const float*)d_in[10];
  const float* b1 = (const float*)d_in[11];
  const float* w2 = (const float*)d_in[12];
  const float* b2 = (const float*)d_in[13];
  const float* ln1_g = (const float*)d_in[14];
  const float* ln1_b = (const float*)d_in[15];
  const float* ln2_g = (const float*)d_in[16];
  const float* ln2_b = (const float*)d_in[17];
  float* out = (float*)d_out;

  u16* ws = (u16*)d_ws;
  u16* wqkvT = ws;                      // [0,3M) u16
  u16* woT = wqkvT + 3072 * 1024;       // [3M,4M)
  u16* w1T = woT + 1024 * 1024;         // [4M,8M)
  u16* w2T = w1T + 4096 * 1024;         // [8M,12M)
  u16* h   = w2T + 4096 * 1024;         // [12M,16M)  LN1 out; WO partial0; LN2 out; FFN2 p2
  u16* qb  = h + 4096 * 1024;           // [16M,20M)  Q; WO partial1
  u16* kb  = qb + 4096 * 1024;          // [20M,24M)  K; WO partial2
  u16* vb  = kb + 4096 * 1024;          // [24M,28M)  V^T; WO partial3
  u16* ctx = vb + 4096 * 1024;          // [28M,32M)
  u16* ffh = qb;                        // [16M,32M)  4096x4096 relu acts (qb..ctx dead)

  // one launch: wq/wk/wv/wo/w1/w2 transposes + LN1
  prep<<<16384, 256, 0, stream>>>(wq, wk, wv, wo, w1, w2, x, ln1_g, ln1_b,
                                  wqkvT, w1T, w2T, h);

  // QKV: quadrant gemm8, XCD-chunked; scatter epilogue writes qb/kb (bh,s,d) and vb (bh,d,s)
  gemm8<0, 1><<<dim3(12, 16), 512, 0, stream>>>(h, wqkvT, 4096, 3072, 1024, nullptr,
                                                bq, bk, bv, qb, kb, vb);

  flash_attn<<<dim3(16, 32), 256, 0, stream>>>(qb, kb, vb, mask, ctx);

  // WO: split-K x4 (grid 4x16x4 = 256 blocks), bf16 partials into h/qb/kb/vb (all dead)
  gemm8<1, 0><<<dim3(4, 16, 4), 512, 0, stream>>>(ctx, woT, 4096, 1024, 1024, h,
                                                  nullptr, nullptr, nullptr, qb, kb, vb);

  // fused: y = x + bo + P0..P3 -> out (fp32 residual) and h = LN2(y) bf16 (p0 aliases hout)
  ln_fuse<<<4096, 256, 0, stream>>>(x, bo, h, qb, kb, vb, ln2_g, ln2_b, out, h);

  // FFN1: quadrant gemm8, XCD-chunked, grid 16x16 = 256 blocks, relu+bias epilogue
  gemm8<2, 1><<<dim3(16, 16), 512, 0, stream>>>(h, w1T, 4096, 4096, 1024, ffh, b1,
                                                nullptr, nullptr, nullptr, nullptr, nullptr);

  // FFN2: split-K x4; z0..z2 bf16 partials into the ONLY dead regions (wqkvT+woT, w1T, h);
  // z3 accumulates fp32 atomically into out (w2T and ffh are live -- no 4th dead slot).
  gemm8<3, 0><<<dim3(4, 16, 4), 512, 0, stream>>>(ffh, w2T, 4096, 1024, 4096, ws,
                                                  nullptr, nullptr, nullptr, w1T, h, (u16*)out);

  final_add<<<4096, 256, 0, stream>>>(out, b2, ws, w1T, h);
}